// Round 1
// baseline (760.506 us; speedup 1.0000x reference)
//
#include <hip/hip_runtime.h>
#include <hip/hip_bf16.h>
#include <cstdint>

#define ND 48
#define LQ 2304      // 48*48
#define CCH 96
#define HWD 96
#define NJ 1536      // 96*16

typedef __attribute__((ext_vector_type(8))) short bf16x8;
typedef __attribute__((ext_vector_type(4))) float f32x4;

// ---------------- K0: downsample fg/bg to (c,p) layout + per-pos squared norm of bgd
__global__ void k_down(const float* __restrict__ fg, const float* __restrict__ bg,
                       float* __restrict__ fgdT, float* __restrict__ bgdT,
                       float* __restrict__ n2) {
  int p = blockIdx.x * 256 + threadIdx.x;
  if (p >= LQ) return;
  int py = p / ND, px = p % ND;
  const float* fsrc = fg + (2 * py) * HWD + 2 * px;
  const float* gsrc = bg + (2 * py) * HWD + 2 * px;
  float s = 0.f;
  for (int c = 0; c < CCH; ++c) {
    float f = fsrc[c * HWD * HWD];
    float g = gsrc[c * HWD * HWD];
    fgdT[c * LQ + p] = f;
    bgdT[c * LQ + p] = g;
    s += g * g;
  }
  n2[p] = s;
}

// ---------------- K0b: patch norms (rnorm) and mask means (mval)
__global__ void k_aux(const float* __restrict__ n2, const float* __restrict__ mask,
                      float* __restrict__ rnorm, float* __restrict__ mval) {
  int p = blockIdx.x * 256 + threadIdx.x;
  if (p >= LQ) return;
  int py = p / ND, px = p % ND;
  float ssq = 0.f, ms = 0.f;
  for (int dy = -1; dy <= 1; ++dy)
    for (int dx = -1; dx <= 1; ++dx) {
      int yy = py + dy, xx = px + dx;
      if (yy >= 0 && yy < ND && xx >= 0 && xx < ND) {
        ssq += n2[yy * ND + xx];
        ms  += mask[(2 * yy) * HWD + 2 * xx];
      }
    }
  rnorm[p] = 1.0f / sqrtf(ssq + 864.0f * 1e-9f);
  mval[p]  = ms * (1.0f / 9.0f);
}

// ---------------- K1: R[q][l] = sum_c fgdT[c][q] * bgdT[c][l]   (fp32, K=96)
__global__ __launch_bounds__(256) void k_rgemm(const float* __restrict__ fgdT,
                                               const float* __restrict__ bgdT,
                                               float* __restrict__ R) {
  __shared__ float As[16][64];
  __shared__ float Bs[16][64];
  int l0 = blockIdx.x * 64, q0 = blockIdx.y * 64;
  int tid = threadIdx.x;
  int ty = tid / 16, tx = tid % 16;
  float acc[4][4] = {};
  for (int k0 = 0; k0 < CCH; k0 += 16) {
#pragma unroll
    for (int i = 0; i < 4; ++i) {
      int idx = tid + i * 256;
      int kk = idx >> 6, cc = idx & 63;
      As[kk][cc] = fgdT[(k0 + kk) * LQ + q0 + cc];
      Bs[kk][cc] = bgdT[(k0 + kk) * LQ + l0 + cc];
    }
    __syncthreads();
#pragma unroll
    for (int kk = 0; kk < 16; ++kk) {
      float a[4], bb[4];
#pragma unroll
      for (int i = 0; i < 4; ++i) a[i] = As[kk][ty * 4 + i];
#pragma unroll
      for (int j = 0; j < 4; ++j) bb[j] = Bs[kk][tx * 4 + j];
#pragma unroll
      for (int i = 0; i < 4; ++i)
#pragma unroll
        for (int j = 0; j < 4; ++j) acc[i][j] += a[i] * bb[j];
    }
    __syncthreads();
  }
#pragma unroll
  for (int i = 0; i < 4; ++i) {
    float4 v = make_float4(acc[i][0], acc[i][1], acc[i][2], acc[i][3]);
    *(float4*)&R[(size_t)(q0 + ty * 4 + i) * LQ + l0 + tx * 4] = v;
  }
}

// ---------------- K2: simT[q][l] = rnorm[l] * sum_{3x3 diag taps, 2D-valid} R[q+d][l+d]
__global__ void k_sim(const float* __restrict__ R, const float* __restrict__ rnorm,
                      float* __restrict__ simT) {
  int id = blockIdx.x * 256 + threadIdx.x;
  int q = id / LQ, l = id % LQ;
  int qy = q / ND, qx = q % ND, ly = l / ND, lx = l % ND;
  float v = 0.f;
#pragma unroll
  for (int dy = -1; dy <= 1; ++dy)
#pragma unroll
    for (int dx = -1; dx <= 1; ++dx) {
      if (qy + dy < 0 || qy + dy >= ND || qx + dx < 0 || qx + dx >= ND ||
          ly + dy < 0 || ly + dy >= ND || lx + dx < 0 || lx + dx >= ND) continue;
      int off = dy * ND + dx;
      v += R[(size_t)(q + off) * LQ + l + off];
    }
  simT[id] = v * rnorm[l];
}

// ---------------- K3: flat-index double diag-fuse + masked softmax over l, write P in bf16
// fused[l,q] = sum_{d2} sum_{d1} sim[swap(fl+d2)+d1, swap(fq+d2)+d1] (flat bounds),
// logit = fused * 10 * m_l ; P = softmax_l(logit) * m_l
__global__ __launch_bounds__(256) void k_softmax(const float* __restrict__ simT,
                                                 const float* __restrict__ mval,
                                                 __hip_bfloat16* __restrict__ Pbf) {
  int q = blockIdx.x;
  int qy = q / ND, qx = q % ND;
  int tid = threadIdx.x;
  __shared__ float red[256];
  float logit[9];
  float vmax = -1e30f;
#pragma unroll
  for (int s = 0; s < 9; ++s) {
    int l = tid + s * 256;
    int ly = l / ND, lx = l % ND;
    float v = 0.f;
#pragma unroll
    for (int d2 = -1; d2 <= 1; ++d2) {
      int fq = qx * ND + qy + d2;
      int fl = lx * ND + ly + d2;
      if (fq < 0 || fq >= LQ || fl < 0 || fl >= LQ) continue;
      int gq = (fq % ND) * ND + fq / ND;
      int gl = (fl % ND) * ND + fl / ND;
#pragma unroll
      for (int d1 = -1; d1 <= 1; ++d1) {
        int hq = gq + d1, hl = gl + d1;
        if (hq < 0 || hq >= LQ || hl < 0 || hl >= LQ) continue;
        v += simT[(size_t)hq * LQ + hl];
      }
    }
    float lg = v * (10.0f * mval[l]);
    logit[s] = lg;
    vmax = fmaxf(vmax, lg);
  }
  red[tid] = vmax;
  __syncthreads();
  for (int w = 128; w > 0; w >>= 1) {
    if (tid < w) red[tid] = fmaxf(red[tid], red[tid + w]);
    __syncthreads();
  }
  float m = red[0];
  __syncthreads();
  float e[9], ssum = 0.f;
#pragma unroll
  for (int s = 0; s < 9; ++s) { e[s] = __expf(logit[s] - m); ssum += e[s]; }
  red[tid] = ssum;
  __syncthreads();
  for (int w = 128; w > 0; w >>= 1) {
    if (tid < w) red[tid] += red[tid + w];
    __syncthreads();
  }
  float inv = 1.0f / red[0];
#pragma unroll
  for (int s = 0; s < 9; ++s) {
    int l = tid + s * 256;
    float p = e[s] * inv * mval[l];
    Pbf[(size_t)q * LQ + l] = __float2bfloat16(p);
  }
}

// ---------------- K4: wrBT[j][l] = bg[c, 2(ly+u-1), 2(lx+v-1)]  (bf16), j = c*16+u*4+v
__global__ void k_wrb(const float* __restrict__ bg, __hip_bfloat16* __restrict__ wrBT) {
  int id = blockIdx.x * 256 + threadIdx.x;
  int j = id / LQ, l = id % LQ;
  int c = j >> 4, uv = j & 15, u = uv >> 2, v = uv & 3;
  int ly = l / ND, lx = l % ND;
  int ry = ly + u - 1, rx = lx + v - 1;
  float val = 0.f;
  if (ry >= 0 && ry < ND && rx >= 0 && rx < ND)
    val = bg[(size_t)c * HWD * HWD + (2 * ry) * HWD + 2 * rx];
  wrBT[id] = __float2bfloat16(val);
}

// ---------------- K5: bf16 MFMA GEMM: OP[q][j] = sum_l Pbf[q][l] * wrBT[j][l]
// M=2304, N=1536, K=2304; 128x128 tile, 4 waves, BK=64, global_load_lds width 16
__device__ __forceinline__ void gload16(const void* g, void* l) {
  __builtin_amdgcn_global_load_lds((const __attribute__((address_space(1))) void*)g,
                                   (__attribute__((address_space(3))) void*)l, 16, 0, 0);
}

__global__ __launch_bounds__(256) void k_gemm2(const __hip_bfloat16* __restrict__ A,
                                               const __hip_bfloat16* __restrict__ B,
                                               float* __restrict__ Cmat) {
  constexpr int M = LQ, N = NJ, K = LQ;
  __shared__ __align__(16) __hip_bfloat16 As[128 * 64];
  __shared__ __align__(16) __hip_bfloat16 Bs[128 * 64];
  int m0 = blockIdx.y * 128, n0 = blockIdx.x * 128;
  int tid = threadIdx.x;
  int w = tid >> 6, lane = tid & 63;
  int wm = w >> 1, wn = w & 1;
  f32x4 acc[4][4] = {};
  for (int k0 = 0; k0 < K; k0 += 64) {
#pragma unroll
    for (int i = 0; i < 4; ++i) {
      int chunk = w * 4 + i;                 // 16 chunks x 8 rows = 128 rows
      int row = chunk * 8 + (lane >> 3);
      int kc = k0 + (lane & 7) * 8;
      gload16(A + (size_t)(m0 + row) * K + kc, As + chunk * 8 * 64);
      gload16(B + (size_t)(n0 + row) * K + kc, Bs + chunk * 8 * 64);
    }
    __syncthreads();
#pragma unroll
    for (int kk = 0; kk < 64; kk += 32) {
      bf16x8 af[4], bfr[4];
#pragma unroll
      for (int mi = 0; mi < 4; ++mi)
        af[mi] = *(const bf16x8*)(As + (wm * 64 + mi * 16 + (lane & 15)) * 64 + kk + (lane >> 4) * 8);
#pragma unroll
      for (int ni = 0; ni < 4; ++ni)
        bfr[ni] = *(const bf16x8*)(Bs + (wn * 64 + ni * 16 + (lane & 15)) * 64 + kk + (lane >> 4) * 8);
#pragma unroll
      for (int mi = 0; mi < 4; ++mi)
#pragma unroll
        for (int ni = 0; ni < 4; ++ni)
          acc[mi][ni] = __builtin_amdgcn_mfma_f32_16x16x32_bf16(af[mi], bfr[ni], acc[mi][ni], 0, 0, 0);
    }
    __syncthreads();
  }
#pragma unroll
  for (int mi = 0; mi < 4; ++mi)
#pragma unroll
    for (int ni = 0; ni < 4; ++ni)
#pragma unroll
      for (int r = 0; r < 4; ++r) {
        int row = m0 + wm * 64 + mi * 16 + (lane >> 4) * 4 + r;
        int col = n0 + wn * 64 + ni * 16 + (lane & 15);
        Cmat[(size_t)row * N + col] = acc[mi][ni][r];
      }
}

// ---------------- K6: fold out_patch into image: y[c,Y,X] = (1/16) * sum_{<=4 taps}
__global__ void k_fold(const float* __restrict__ OP, float* __restrict__ out) {
  int id = blockIdx.x * 256 + threadIdx.x;
  if (id >= CCH * HWD * HWD) return;
  int c = id / (HWD * HWD), rem = id % (HWD * HWD);
  int Y = rem / HWD, X = rem % HWD;
  float acc = 0.f;
#pragma unroll
  for (int du = 0; du < 2; ++du) {
    int u = (Y & 1) + 2 * du;
    int qy = (Y - u) >> 1;
    if (qy < 0 || qy >= ND) continue;
#pragma unroll
    for (int dv = 0; dv < 2; ++dv) {
      int v = (X & 1) + 2 * dv;
      int qx = (X - v) >> 1;
      if (qx < 0 || qx >= ND) continue;
      acc += OP[(size_t)(qy * ND + qx) * NJ + (c << 4) + (u << 2) + v];
    }
  }
  out[id] = acc * (1.0f / 16.0f);
}

extern "C" void kernel_launch(void* const* d_in, const int* in_sizes, int n_in,
                              void* d_out, int out_size, void* d_ws, size_t ws_size,
                              hipStream_t stream) {
  const float* fg_all = (const float*)d_in[0];
  const float* bg_all = (const float*)d_in[1];
  const float* mask_all = (const float*)d_in[2];
  float* out_all = (float*)d_out;
  float* ws = (float*)d_ws;

  // workspace layout (float offsets)
  float* fgdT  = ws;                        // 221184
  float* bgdT  = ws + 221184;               // 221184
  float* n2    = ws + 442368;               // 2304
  float* rnorm = ws + 444672;               // 2304
  float* mval  = ws + 446976;               // 2304
  float* buf0  = ws + 449280;               // 5308416 (R, then out_patch)
  float* simT  = ws + 5757696;              // 5308416
  __hip_bfloat16* Pbf  = (__hip_bfloat16*)(ws + 11066112);  // 2304*2304 bf16
  __hip_bfloat16* wrBT = (__hip_bfloat16*)(ws + 13720320);  // 1536*2304 bf16
  // total: 15489792 floats = ~62 MB

  int B = in_sizes[0] / (CCH * HWD * HWD);
  for (int b = 0; b < B; ++b) {
    const float* fg = fg_all + (size_t)b * CCH * HWD * HWD;
    const float* bg = bg_all + (size_t)b * CCH * HWD * HWD;
    const float* mask = mask_all + (size_t)b * HWD * HWD;
    float* out = out_all + (size_t)b * CCH * HWD * HWD;

    hipLaunchKernelGGL(k_down, dim3(9), dim3(256), 0, stream, fg, bg, fgdT, bgdT, n2);
    hipLaunchKernelGGL(k_aux, dim3(9), dim3(256), 0, stream, n2, mask, rnorm, mval);
    hipLaunchKernelGGL(k_rgemm, dim3(36, 36), dim3(256), 0, stream, fgdT, bgdT, buf0);
    hipLaunchKernelGGL(k_sim, dim3(20736), dim3(256), 0, stream, buf0, rnorm, simT);
    hipLaunchKernelGGL(k_softmax, dim3(2304), dim3(256), 0, stream, simT, mval, Pbf);
    hipLaunchKernelGGL(k_wrb, dim3(13824), dim3(256), 0, stream, bg, wrBT);
    hipLaunchKernelGGL(k_gemm2, dim3(12, 18), dim3(256), 0, stream, Pbf, wrBT, buf0);
    hipLaunchKernelGGL(k_fold, dim3(3456), dim3(256), 0, stream, buf0, out);
  }
}

// Round 2
// 507.178 us; speedup vs baseline: 1.4995x; 1.4995x over previous
//
#include <hip/hip_runtime.h>
#include <hip/hip_bf16.h>
#include <cstdint>

#define ND 48
#define LQ 2304      // 48*48
#define CCH 96
#define HWD 96
#define NJ 1536      // 96*16
#define CHW (CCH*HWD*HWD)   // 884736
#define HW2 (HWD*HWD)       // 9216

typedef __attribute__((ext_vector_type(8))) short bf16x8;
typedef __attribute__((ext_vector_type(4))) float f32x4;

// ---------------- K0: downsample fg/bg to (c,p) layout + per-pos squared norm of bgd
__global__ void k_down(const float* __restrict__ fg, const float* __restrict__ bg,
                       float* __restrict__ fgdT, float* __restrict__ bgdT,
                       float* __restrict__ n2, size_t sd, size_t sp) {
  int b = blockIdx.z;
  const float* fgb = fg + (size_t)b * CHW;
  const float* bgb = bg + (size_t)b * CHW;
  float* fT = fgdT + (size_t)b * sd;
  float* bT = bgdT + (size_t)b * sd;
  float* n2b = n2 + (size_t)b * sp;
  int p = blockIdx.x * 256 + threadIdx.x;
  if (p >= LQ) return;
  int py = p / ND, px = p % ND;
  const float* fsrc = fgb + (2 * py) * HWD + 2 * px;
  const float* gsrc = bgb + (2 * py) * HWD + 2 * px;
  float s = 0.f;
  for (int c = 0; c < CCH; ++c) {
    float f = fsrc[c * HW2];
    float g = gsrc[c * HW2];
    fT[c * LQ + p] = f;
    bT[c * LQ + p] = g;
    s += g * g;
  }
  n2b[p] = s;
}

// ---------------- K0b: patch norms (rnorm) and mask means (mval)
__global__ void k_aux(const float* __restrict__ n2, const float* __restrict__ mask,
                      float* __restrict__ rnorm, float* __restrict__ mval, size_t sp) {
  int b = blockIdx.z;
  const float* n2b = n2 + (size_t)b * sp;
  const float* mb = mask + (size_t)b * HW2;
  float* rn = rnorm + (size_t)b * sp;
  float* mv = mval + (size_t)b * sp;
  int p = blockIdx.x * 256 + threadIdx.x;
  if (p >= LQ) return;
  int py = p / ND, px = p % ND;
  float ssq = 0.f, ms = 0.f;
  for (int dy = -1; dy <= 1; ++dy)
    for (int dx = -1; dx <= 1; ++dx) {
      int yy = py + dy, xx = px + dx;
      if (yy >= 0 && yy < ND && xx >= 0 && xx < ND) {
        ssq += n2b[yy * ND + xx];
        ms  += mb[(2 * yy) * HWD + 2 * xx];
      }
    }
  rn[p] = 1.0f / sqrtf(ssq + 864.0f * 1e-9f);
  mv[p] = ms * (1.0f / 9.0f);
}

// ---------------- K1: R[q][l] = sum_c fgdT[c][q] * bgdT[c][l]   (fp32, K=96)
__global__ __launch_bounds__(256) void k_rgemm(const float* __restrict__ fgdT,
                                               const float* __restrict__ bgdT,
                                               float* __restrict__ R,
                                               size_t sd, size_t sR) {
  int b = blockIdx.z;
  const float* fT = fgdT + (size_t)b * sd;
  const float* bT = bgdT + (size_t)b * sd;
  float* Rb = R + (size_t)b * sR;
  __shared__ float As[16][64];
  __shared__ float Bs[16][64];
  int l0 = blockIdx.x * 64, q0 = blockIdx.y * 64;
  int tid = threadIdx.x;
  int ty = tid / 16, tx = tid % 16;
  float acc[4][4] = {};
  for (int k0 = 0; k0 < CCH; k0 += 16) {
#pragma unroll
    for (int i = 0; i < 4; ++i) {
      int idx = tid + i * 256;
      int kk = idx >> 6, cc = idx & 63;
      As[kk][cc] = fT[(k0 + kk) * LQ + q0 + cc];
      Bs[kk][cc] = bT[(k0 + kk) * LQ + l0 + cc];
    }
    __syncthreads();
#pragma unroll
    for (int kk = 0; kk < 16; ++kk) {
      float a[4], bb[4];
#pragma unroll
      for (int i = 0; i < 4; ++i) a[i] = As[kk][ty * 4 + i];
#pragma unroll
      for (int j = 0; j < 4; ++j) bb[j] = Bs[kk][tx * 4 + j];
#pragma unroll
      for (int i = 0; i < 4; ++i)
#pragma unroll
        for (int j = 0; j < 4; ++j) acc[i][j] += a[i] * bb[j];
    }
    __syncthreads();
  }
#pragma unroll
  for (int i = 0; i < 4; ++i) {
    float4 v = make_float4(acc[i][0], acc[i][1], acc[i][2], acc[i][3]);
    *(float4*)&Rb[(size_t)(q0 + ty * 4 + i) * LQ + l0 + tx * 4] = v;
  }
}

// ---------------- K2: simT[q][l] = rnorm[l] * sum_{3x3 diag taps, 2D-valid} R[q+d][l+d]
__global__ void k_sim(const float* __restrict__ R, const float* __restrict__ rnorm,
                      float* __restrict__ simT, size_t sR, size_t sp) {
  int b = blockIdx.z;
  const float* Rb = R + (size_t)b * sR;
  const float* rn = rnorm + (size_t)b * sp;
  float* St = simT + (size_t)b * sR;
  int id = blockIdx.x * 256 + threadIdx.x;
  int q = id / LQ, l = id % LQ;
  int qy = q / ND, qx = q % ND, ly = l / ND, lx = l % ND;
  float v = 0.f;
#pragma unroll
  for (int dy = -1; dy <= 1; ++dy)
#pragma unroll
    for (int dx = -1; dx <= 1; ++dx) {
      if (qy + dy < 0 || qy + dy >= ND || qx + dx < 0 || qx + dx >= ND ||
          ly + dy < 0 || ly + dy >= ND || lx + dx < 0 || lx + dx >= ND) continue;
      int off = dy * ND + dx;
      v += Rb[(size_t)(q + off) * LQ + l + off];
    }
  St[id] = v * rn[l];
}

// ---------------- K2b: first flat diag-fuse, streaming: F[a,b] = sum_{d1} simT[a+d1, b+d1]
__global__ void k_fuse(const float* __restrict__ simT, float* __restrict__ F, size_t sR) {
  int b = blockIdx.z;
  const float* S = simT + (size_t)b * sR;
  float* Fo = F + (size_t)b * sR;
  int id = blockIdx.x * 256 + threadIdx.x;
  int a = id / LQ, bc = id % LQ;
  float v = S[id];
  if (a > 0 && bc > 0)            v += S[id - LQ - 1];
  if (a < LQ - 1 && bc < LQ - 1)  v += S[id + LQ + 1];
  Fo[id] = v;
}

// ---------------- K3: second fuse (3 scattered taps) + masked softmax over l, write P bf16
__global__ __launch_bounds__(256) void k_softmax(const float* __restrict__ F,
                                                 const float* __restrict__ mval,
                                                 __hip_bfloat16* __restrict__ Pbf,
                                                 size_t sR, size_t sp, size_t sP) {
  int b = blockIdx.z;
  const float* Fb = F + (size_t)b * sR;
  const float* mv = mval + (size_t)b * sp;
  __hip_bfloat16* Pb = Pbf + (size_t)b * sP;
  int q = blockIdx.x;
  int qy = q / ND, qx = q % ND;
  int tid = threadIdx.x;
  __shared__ float red[256];
  // per-block: 3 candidate fused-q rows
  int gqv[3]; bool qok[3];
#pragma unroll
  for (int t = 0; t < 3; ++t) {
    int fq = qx * ND + qy + (t - 1);
    qok[t] = (fq >= 0 && fq < LQ);
    gqv[t] = qok[t] ? (fq % ND) * ND + fq / ND : 0;
  }
  float logit[9];
  float vmax = -1e30f;
#pragma unroll
  for (int s = 0; s < 9; ++s) {
    int l = tid + s * 256;
    int ly = l / ND, lx = l % ND;
    float v = 0.f;
#pragma unroll
    for (int t = 0; t < 3; ++t) {
      if (!qok[t]) continue;
      int fl = lx * ND + ly + (t - 1);
      if (fl < 0 || fl >= LQ) continue;
      int gl = (fl % ND) * ND + fl / ND;
      v += Fb[(size_t)gqv[t] * LQ + gl];
    }
    float lg = v * (10.0f * mv[l]);
    logit[s] = lg;
    vmax = fmaxf(vmax, lg);
  }
  red[tid] = vmax;
  __syncthreads();
  for (int w = 128; w > 0; w >>= 1) {
    if (tid < w) red[tid] = fmaxf(red[tid], red[tid + w]);
    __syncthreads();
  }
  float m = red[0];
  __syncthreads();
  float e[9], ssum = 0.f;
#pragma unroll
  for (int s = 0; s < 9; ++s) { e[s] = __expf(logit[s] - m); ssum += e[s]; }
  red[tid] = ssum;
  __syncthreads();
  for (int w = 128; w > 0; w >>= 1) {
    if (tid < w) red[tid] += red[tid + w];
    __syncthreads();
  }
  float inv = 1.0f / red[0];
#pragma unroll
  for (int s = 0; s < 9; ++s) {
    int l = tid + s * 256;
    float p = e[s] * inv * mv[l];
    Pb[(size_t)q * LQ + l] = __float2bfloat16(p);
  }
}

// ---------------- K4: wrBT[j][l] = bg[c, 2(ly+u-1), 2(lx+v-1)]  (bf16), j = c*16+u*4+v
__global__ void k_wrb(const float* __restrict__ bg, __hip_bfloat16* __restrict__ wrBT,
                      size_t sw) {
  int b = blockIdx.z;
  const float* bgb = bg + (size_t)b * CHW;
  __hip_bfloat16* wb = wrBT + (size_t)b * sw;
  int id = blockIdx.x * 256 + threadIdx.x;
  int j = id / LQ, l = id % LQ;
  int c = j >> 4, uv = j & 15, u = uv >> 2, v = uv & 3;
  int ly = l / ND, lx = l % ND;
  int ry = ly + u - 1, rx = lx + v - 1;
  float val = 0.f;
  if (ry >= 0 && ry < ND && rx >= 0 && rx < ND)
    val = bgb[(size_t)c * HW2 + (2 * ry) * HWD + 2 * rx];
  wb[id] = __float2bfloat16(val);
}

// ---------------- K5: bf16 MFMA GEMM: OP[q][j] = sum_l Pbf[q][l] * wrBT[j][l]
__device__ __forceinline__ void gload16(const void* g, void* l) {
  __builtin_amdgcn_global_load_lds((const __attribute__((address_space(1))) void*)g,
                                   (__attribute__((address_space(3))) void*)l, 16, 0, 0);
}

__global__ __launch_bounds__(256) void k_gemm2(const __hip_bfloat16* __restrict__ A,
                                               const __hip_bfloat16* __restrict__ B,
                                               float* __restrict__ Cmat,
                                               size_t sP, size_t sw, size_t sOP) {
  constexpr int K = LQ;
  int b = blockIdx.z;
  const __hip_bfloat16* Ab = A + (size_t)b * sP;
  const __hip_bfloat16* Bb = B + (size_t)b * sw;
  float* Cb = Cmat + (size_t)b * sOP;
  __shared__ __align__(16) __hip_bfloat16 As[128 * 64];
  __shared__ __align__(16) __hip_bfloat16 Bs[128 * 64];
  int m0 = blockIdx.y * 128, n0 = blockIdx.x * 128;
  int tid = threadIdx.x;
  int w = tid >> 6, lane = tid & 63;
  int wm = w >> 1, wn = w & 1;
  f32x4 acc[4][4] = {};
  for (int k0 = 0; k0 < K; k0 += 64) {
#pragma unroll
    for (int i = 0; i < 4; ++i) {
      int chunk = w * 4 + i;                 // 16 chunks x 8 rows = 128 rows
      int row = chunk * 8 + (lane >> 3);
      int kc = k0 + (lane & 7) * 8;
      gload16(Ab + (size_t)(m0 + row) * K + kc, As + chunk * 8 * 64);
      gload16(Bb + (size_t)(n0 + row) * K + kc, Bs + chunk * 8 * 64);
    }
    __syncthreads();
#pragma unroll
    for (int kk = 0; kk < 64; kk += 32) {
      bf16x8 af[4], bfr[4];
#pragma unroll
      for (int mi = 0; mi < 4; ++mi)
        af[mi] = *(const bf16x8*)(As + (wm * 64 + mi * 16 + (lane & 15)) * 64 + kk + (lane >> 4) * 8);
#pragma unroll
      for (int ni = 0; ni < 4; ++ni)
        bfr[ni] = *(const bf16x8*)(Bs + (wn * 64 + ni * 16 + (lane & 15)) * 64 + kk + (lane >> 4) * 8);
#pragma unroll
      for (int mi = 0; mi < 4; ++mi)
#pragma unroll
        for (int ni = 0; ni < 4; ++ni)
          acc[mi][ni] = __builtin_amdgcn_mfma_f32_16x16x32_bf16(af[mi], bfr[ni], acc[mi][ni], 0, 0, 0);
    }
    __syncthreads();
  }
#pragma unroll
  for (int mi = 0; mi < 4; ++mi)
#pragma unroll
    for (int ni = 0; ni < 4; ++ni)
#pragma unroll
      for (int r = 0; r < 4; ++r) {
        int row = m0 + wm * 64 + mi * 16 + (lane >> 4) * 4 + r;
        int col = n0 + wn * 64 + ni * 16 + (lane & 15);
        Cb[(size_t)row * NJ + col] = acc[mi][ni][r];
      }
}

// ---------------- K6: fold out_patch into image: y[c,Y,X] = (1/16) * sum_{<=4 taps}
__global__ void k_fold(const float* __restrict__ OP, float* __restrict__ out, size_t sOP) {
  int b = blockIdx.z;
  const float* OPb = OP + (size_t)b * sOP;
  float* ob = out + (size_t)b * CHW;
  int id = blockIdx.x * 256 + threadIdx.x;
  if (id >= CHW) return;
  int c = id / HW2, rem = id % HW2;
  int Y = rem / HWD, X = rem % HWD;
  float acc = 0.f;
#pragma unroll
  for (int du = 0; du < 2; ++du) {
    int u = (Y & 1) + 2 * du;
    int qy = (Y - u) >> 1;
    if (qy < 0 || qy >= ND) continue;
#pragma unroll
    for (int dv = 0; dv < 2; ++dv) {
      int v = (X & 1) + 2 * dv;
      int qx = (X - v) >> 1;
      if (qx < 0 || qx >= ND) continue;
      acc += OPb[(size_t)(qy * ND + qx) * NJ + (c << 4) + (u << 2) + v];
    }
  }
  ob[id] = acc * (1.0f / 16.0f);
}

extern "C" void kernel_launch(void* const* d_in, const int* in_sizes, int n_in,
                              void* d_out, int out_size, void* d_ws, size_t ws_size,
                              hipStream_t stream) {
  const float* fg_all = (const float*)d_in[0];
  const float* bg_all = (const float*)d_in[1];
  const float* mask_all = (const float*)d_in[2];
  float* out_all = (float*)d_out;
  float* ws = (float*)d_ws;

  int B = in_sizes[0] / CHW;

  // per-sample sizes (elements)
  const size_t S_D = (size_t)CCH * LQ;      // 221184 f32
  const size_t S_P = LQ;                    // 2304  f32
  const size_t S_R = (size_t)LQ * LQ;       // 5308416 f32
  const size_t S_PBF = (size_t)LQ * LQ;     // 5308416 bf16
  const size_t S_W = (size_t)NJ * LQ;       // 3538944 bf16
  const size_t per_floats = S_D * 2 + S_P * 3 + S_R * 2 + S_PBF / 2 + S_W / 2; // 15489792

  bool batched = ws_size >= (size_t)B * per_floats * 4;
  int na = batched ? B : 1;   // allocation multiplier
  int nb = na;                // z-extent per launch

  float* fgdT  = ws;
  float* bgdT  = fgdT + (size_t)na * S_D;
  float* n2    = bgdT + (size_t)na * S_D;
  float* rnorm = n2 + (size_t)na * S_P;
  float* mval  = rnorm + (size_t)na * S_P;
  float* bufA  = mval + (size_t)na * S_P;              // R, then F
  float* bufB  = bufA + (size_t)na * S_R;              // simT, then OP
  __hip_bfloat16* Pbf  = (__hip_bfloat16*)(bufB + (size_t)na * S_R);
  __hip_bfloat16* wrBT = Pbf + (size_t)na * S_PBF;

  size_t sd = batched ? S_D : 0, sp = batched ? S_P : 0, sR = batched ? S_R : 0;
  size_t sP = batched ? S_PBF : 0, sw = batched ? S_W : 0;

  for (int b0 = 0; b0 < B; b0 += nb) {
    const float* fg = fg_all + (size_t)(batched ? 0 : b0) * CHW;
    const float* bg = bg_all + (size_t)(batched ? 0 : b0) * CHW;
    const float* mask = mask_all + (size_t)(batched ? 0 : b0) * HW2;
    float* out = out_all + (size_t)(batched ? 0 : b0) * CHW;

    hipLaunchKernelGGL(k_down, dim3(9, 1, nb), dim3(256), 0, stream,
                       fg, bg, fgdT, bgdT, n2, sd, sp);
    hipLaunchKernelGGL(k_aux, dim3(9, 1, nb), dim3(256), 0, stream,
                       n2, mask, rnorm, mval, sp);
    hipLaunchKernelGGL(k_rgemm, dim3(36, 36, nb), dim3(256), 0, stream,
                       fgdT, bgdT, bufA, sd, sR);
    hipLaunchKernelGGL(k_sim, dim3(20736, 1, nb), dim3(256), 0, stream,
                       bufA, rnorm, bufB, sR, sp);
    hipLaunchKernelGGL(k_fuse, dim3(20736, 1, nb), dim3(256), 0, stream,
                       bufB, bufA, sR);
    hipLaunchKernelGGL(k_softmax, dim3(2304, 1, nb), dim3(256), 0, stream,
                       bufA, mval, Pbf, sR, sp, sP);
    hipLaunchKernelGGL(k_wrb, dim3(13824, 1, nb), dim3(256), 0, stream,
                       bg, wrBT, sw);
    hipLaunchKernelGGL(k_gemm2, dim3(12, 18, nb), dim3(256), 0, stream,
                       Pbf, wrBT, bufB, sP, sw, sR);
    hipLaunchKernelGGL(k_fold, dim3(3456, 1, nb), dim3(256), 0, stream,
                       bufB, out, sR);
  }
}

// Round 3
// 480.519 us; speedup vs baseline: 1.5827x; 1.0555x over previous
//
#include <hip/hip_runtime.h>
#include <hip/hip_bf16.h>
#include <cstdint>

#define ND 48
#define LQ 2304      // 48*48
#define CCH 96
#define HWD 96
#define NJ 1536      // 96*16
#define CHW (CCH*HWD*HWD)   // 884736
#define HW2 (HWD*HWD)       // 9216

typedef __attribute__((ext_vector_type(8))) short bf16x8;
typedef __attribute__((ext_vector_type(4))) float f32x4;

// ---------------- K0: downsample fg/bg to (c,p) layout + per-pos squared norm of bgd
__global__ void k_down(const float* __restrict__ fg, const float* __restrict__ bg,
                       float* __restrict__ fgdT, float* __restrict__ bgdT,
                       float* __restrict__ n2, size_t sd, size_t sp) {
  int b = blockIdx.z;
  const float* fgb = fg + (size_t)b * CHW;
  const float* bgb = bg + (size_t)b * CHW;
  float* fT = fgdT + (size_t)b * sd;
  float* bT = bgdT + (size_t)b * sd;
  float* n2b = n2 + (size_t)b * sp;
  int p = blockIdx.x * 256 + threadIdx.x;
  if (p >= LQ) return;
  int py = p / ND, px = p % ND;
  const float* fsrc = fgb + (2 * py) * HWD + 2 * px;
  const float* gsrc = bgb + (2 * py) * HWD + 2 * px;
  float s = 0.f;
  for (int c = 0; c < CCH; ++c) {
    float f = fsrc[c * HW2];
    float g = gsrc[c * HW2];
    fT[c * LQ + p] = f;
    bT[c * LQ + p] = g;
    s += g * g;
  }
  n2b[p] = s;
}

// ---------------- K0b: patch norms (rnorm) and mask means (mval)
__global__ void k_aux(const float* __restrict__ n2, const float* __restrict__ mask,
                      float* __restrict__ rnorm, float* __restrict__ mval, size_t sp) {
  int b = blockIdx.z;
  const float* n2b = n2 + (size_t)b * sp;
  const float* mb = mask + (size_t)b * HW2;
  float* rn = rnorm + (size_t)b * sp;
  float* mv = mval + (size_t)b * sp;
  int p = blockIdx.x * 256 + threadIdx.x;
  if (p >= LQ) return;
  int py = p / ND, px = p % ND;
  float ssq = 0.f, ms = 0.f;
  for (int dy = -1; dy <= 1; ++dy)
    for (int dx = -1; dx <= 1; ++dx) {
      int yy = py + dy, xx = px + dx;
      if (yy >= 0 && yy < ND && xx >= 0 && xx < ND) {
        ssq += n2b[yy * ND + xx];
        ms  += mb[(2 * yy) * HWD + 2 * xx];
      }
    }
  rn[p] = 1.0f / sqrtf(ssq + 864.0f * 1e-9f);
  mv[p] = ms * (1.0f / 9.0f);
}

// ---------------- K1: R[q][l] = sum_c fgdT[c][q] * bgdT[c][l]   (fp32, K=96)
__global__ __launch_bounds__(256) void k_rgemm(const float* __restrict__ fgdT,
                                               const float* __restrict__ bgdT,
                                               float* __restrict__ R,
                                               size_t sd, size_t sR) {
  int b = blockIdx.z;
  const float* fT = fgdT + (size_t)b * sd;
  const float* bT = bgdT + (size_t)b * sd;
  float* Rb = R + (size_t)b * sR;
  __shared__ float As[16][64];
  __shared__ float Bs[16][64];
  int l0 = blockIdx.x * 64, q0 = blockIdx.y * 64;
  int tid = threadIdx.x;
  int ty = tid / 16, tx = tid % 16;
  float acc[4][4] = {};
  for (int k0 = 0; k0 < CCH; k0 += 16) {
#pragma unroll
    for (int i = 0; i < 4; ++i) {
      int idx = tid + i * 256;
      int kk = idx >> 6, cc = idx & 63;
      As[kk][cc] = fT[(k0 + kk) * LQ + q0 + cc];
      Bs[kk][cc] = bT[(k0 + kk) * LQ + l0 + cc];
    }
    __syncthreads();
#pragma unroll
    for (int kk = 0; kk < 16; ++kk) {
      float a[4], bb[4];
#pragma unroll
      for (int i = 0; i < 4; ++i) a[i] = As[kk][ty * 4 + i];
#pragma unroll
      for (int j = 0; j < 4; ++j) bb[j] = Bs[kk][tx * 4 + j];
#pragma unroll
      for (int i = 0; i < 4; ++i)
#pragma unroll
        for (int j = 0; j < 4; ++j) acc[i][j] += a[i] * bb[j];
    }
    __syncthreads();
  }
#pragma unroll
  for (int i = 0; i < 4; ++i) {
    float4 v = make_float4(acc[i][0], acc[i][1], acc[i][2], acc[i][3]);
    *(float4*)&Rb[(size_t)(q0 + ty * 4 + i) * LQ + l0 + tx * 4] = v;
  }
}

// ---------------- K2a: T_col — A1[q][l] = sum_{dx in {-1,0,1}} R[q+dx][l+dx], x-coord masks
__global__ void k_tcol(const float* __restrict__ R, float* __restrict__ A1, size_t sR) {
  int b = blockIdx.z;
  const float* S = R + (size_t)b * sR;
  float* O = A1 + (size_t)b * sR;
  int id = blockIdx.x * 256 + threadIdx.x;
  int q = id / LQ, l = id % LQ;
  int qx = q % ND, lx = l % ND;
  float v = S[id];
  if (qx > 0 && lx > 0)            v += S[id - LQ - 1];
  if (qx < ND - 1 && lx < ND - 1)  v += S[id + LQ + 1];
  O[id] = v;
}

// ---------------- K2b: T_row (+rnorm) — A2[q][l] = rnorm[l]*sum_{dy} A1[q+48dy][l+48dy]
__global__ void k_trow(const float* __restrict__ A1, const float* __restrict__ rnorm,
                       float* __restrict__ A2, size_t sR, size_t sp) {
  int b = blockIdx.z;
  const float* S = A1 + (size_t)b * sR;
  const float* rn = rnorm + (size_t)b * sp;
  float* O = A2 + (size_t)b * sR;
  int id = blockIdx.x * 256 + threadIdx.x;
  int q = id / LQ, l = id % LQ;
  int qy = q / ND, ly = l / ND;
  const int OFF = ND * (LQ + 1);
  float v = S[id];
  if (qy > 0 && ly > 0)            v += S[id - OFF];
  if (qy < ND - 1 && ly < ND - 1)  v += S[id + OFF];
  O[id] = v * rn[l];
}

// ---------------- K2c: flat diag fuse — F[a][b] = sum_{d1} A2[a+d1][b+d1], flat bounds
__global__ void k_fuse(const float* __restrict__ simT, float* __restrict__ F, size_t sR) {
  int b = blockIdx.z;
  const float* S = simT + (size_t)b * sR;
  float* Fo = F + (size_t)b * sR;
  int id = blockIdx.x * 256 + threadIdx.x;
  int a = id / LQ, bc = id % LQ;
  float v = S[id];
  if (a > 0 && bc > 0)            v += S[id - LQ - 1];
  if (a < LQ - 1 && bc < LQ - 1)  v += S[id + LQ + 1];
  Fo[id] = v;
}

// ---------------- K3: second fuse (3 scattered taps) + masked softmax over l, write P bf16
__global__ __launch_bounds__(256) void k_softmax(const float* __restrict__ F,
                                                 const float* __restrict__ mval,
                                                 __hip_bfloat16* __restrict__ Pbf,
                                                 size_t sR, size_t sp, size_t sP) {
  int b = blockIdx.z;
  const float* Fb = F + (size_t)b * sR;
  const float* mv = mval + (size_t)b * sp;
  __hip_bfloat16* Pb = Pbf + (size_t)b * sP;
  int q = blockIdx.x;
  int qy = q / ND, qx = q % ND;
  int tid = threadIdx.x;
  __shared__ float red[256];
  int gqv[3]; bool qok[3];
#pragma unroll
  for (int t = 0; t < 3; ++t) {
    int fq = qx * ND + qy + (t - 1);
    qok[t] = (fq >= 0 && fq < LQ);
    gqv[t] = qok[t] ? (fq % ND) * ND + fq / ND : 0;
  }
  float logit[9];
  float vmax = -1e30f;
#pragma unroll
  for (int s = 0; s < 9; ++s) {
    int l = tid + s * 256;
    int ly = l / ND, lx = l % ND;
    float v = 0.f;
#pragma unroll
    for (int t = 0; t < 3; ++t) {
      if (!qok[t]) continue;
      int fl = lx * ND + ly + (t - 1);
      if (fl < 0 || fl >= LQ) continue;
      int gl = (fl % ND) * ND + fl / ND;
      v += Fb[(size_t)gqv[t] * LQ + gl];
    }
    float lg = v * (10.0f * mv[l]);
    logit[s] = lg;
    vmax = fmaxf(vmax, lg);
  }
  red[tid] = vmax;
  __syncthreads();
  for (int w = 128; w > 0; w >>= 1) {
    if (tid < w) red[tid] = fmaxf(red[tid], red[tid + w]);
    __syncthreads();
  }
  float m = red[0];
  __syncthreads();
  float e[9], ssum = 0.f;
#pragma unroll
  for (int s = 0; s < 9; ++s) { e[s] = __expf(logit[s] - m); ssum += e[s]; }
  red[tid] = ssum;
  __syncthreads();
  for (int w = 128; w > 0; w >>= 1) {
    if (tid < w) red[tid] += red[tid + w];
    __syncthreads();
  }
  float inv = 1.0f / red[0];
#pragma unroll
  for (int s = 0; s < 9; ++s) {
    int l = tid + s * 256;
    float p = e[s] * inv * mv[l];
    Pb[(size_t)q * LQ + l] = __float2bfloat16(p);
  }
}

// ---------------- K4: wrBT[j][l] = bg[c, 2(ly+u-1), 2(lx+v-1)]  (bf16), j = c*16+u*4+v
__global__ void k_wrb(const float* __restrict__ bg, __hip_bfloat16* __restrict__ wrBT,
                      size_t sw) {
  int b = blockIdx.z;
  const float* bgb = bg + (size_t)b * CHW;
  __hip_bfloat16* wb = wrBT + (size_t)b * sw;
  int id = blockIdx.x * 256 + threadIdx.x;
  int j = id / LQ, l = id % LQ;
  int c = j >> 4, uv = j & 15, u = uv >> 2, v = uv & 3;
  int ly = l / ND, lx = l % ND;
  int ry = ly + u - 1, rx = lx + v - 1;
  float val = 0.f;
  if (ry >= 0 && ry < ND && rx >= 0 && rx < ND)
    val = bgb[(size_t)c * HW2 + (2 * ry) * HWD + 2 * rx];
  wb[id] = __float2bfloat16(val);
}

// ---------------- K5: bf16 MFMA GEMM: OP[q][j] = sum_l Pbf[q][l] * wrBT[j][l]
__device__ __forceinline__ void gload16(const void* g, void* l) {
  __builtin_amdgcn_global_load_lds((const __attribute__((address_space(1))) void*)g,
                                   (__attribute__((address_space(3))) void*)l, 16, 0, 0);
}

__global__ __launch_bounds__(256) void k_gemm2(const __hip_bfloat16* __restrict__ A,
                                               const __hip_bfloat16* __restrict__ B,
                                               float* __restrict__ Cmat,
                                               size_t sP, size_t sw, size_t sOP) {
  constexpr int K = LQ;
  int b = blockIdx.z;
  const __hip_bfloat16* Ab = A + (size_t)b * sP;
  const __hip_bfloat16* Bb = B + (size_t)b * sw;
  float* Cb = Cmat + (size_t)b * sOP;
  __shared__ __align__(16) __hip_bfloat16 As[128 * 64];
  __shared__ __align__(16) __hip_bfloat16 Bs[128 * 64];
  int m0 = blockIdx.y * 128, n0 = blockIdx.x * 128;
  int tid = threadIdx.x;
  int w = tid >> 6, lane = tid & 63;
  int wm = w >> 1, wn = w & 1;
  f32x4 acc[4][4] = {};
  for (int k0 = 0; k0 < K; k0 += 64) {
#pragma unroll
    for (int i = 0; i < 4; ++i) {
      int chunk = w * 4 + i;                 // 16 chunks x 8 rows = 128 rows
      int row = chunk * 8 + (lane >> 3);
      int kc = k0 + (lane & 7) * 8;
      gload16(Ab + (size_t)(m0 + row) * K + kc, As + chunk * 8 * 64);
      gload16(Bb + (size_t)(n0 + row) * K + kc, Bs + chunk * 8 * 64);
    }
    __syncthreads();
#pragma unroll
    for (int kk = 0; kk < 64; kk += 32) {
      bf16x8 af[4], bfr[4];
#pragma unroll
      for (int mi = 0; mi < 4; ++mi)
        af[mi] = *(const bf16x8*)(As + (wm * 64 + mi * 16 + (lane & 15)) * 64 + kk + (lane >> 4) * 8);
#pragma unroll
      for (int ni = 0; ni < 4; ++ni)
        bfr[ni] = *(const bf16x8*)(Bs + (wn * 64 + ni * 16 + (lane & 15)) * 64 + kk + (lane >> 4) * 8);
#pragma unroll
      for (int mi = 0; mi < 4; ++mi)
#pragma unroll
        for (int ni = 0; ni < 4; ++ni)
          acc[mi][ni] = __builtin_amdgcn_mfma_f32_16x16x32_bf16(af[mi], bfr[ni], acc[mi][ni], 0, 0, 0);
    }
    __syncthreads();
  }
#pragma unroll
  for (int mi = 0; mi < 4; ++mi)
#pragma unroll
    for (int ni = 0; ni < 4; ++ni)
#pragma unroll
      for (int r = 0; r < 4; ++r) {
        int row = m0 + wm * 64 + mi * 16 + (lane >> 4) * 4 + r;
        int col = n0 + wn * 64 + ni * 16 + (lane & 15);
        Cb[(size_t)row * NJ + col] = acc[mi][ni][r];
      }
}

// ---------------- K6: fold out_patch into image: y[c,Y,X] = (1/16) * sum_{<=4 taps}
__global__ void k_fold(const float* __restrict__ OP, float* __restrict__ out, size_t sOP) {
  int b = blockIdx.z;
  const float* OPb = OP + (size_t)b * sOP;
  float* ob = out + (size_t)b * CHW;
  int id = blockIdx.x * 256 + threadIdx.x;
  if (id >= CHW) return;
  int c = id / HW2, rem = id % HW2;
  int Y = rem / HWD, X = rem % HWD;
  float acc = 0.f;
#pragma unroll
  for (int du = 0; du < 2; ++du) {
    int u = (Y & 1) + 2 * du;
    int qy = (Y - u) >> 1;
    if (qy < 0 || qy >= ND) continue;
#pragma unroll
    for (int dv = 0; dv < 2; ++dv) {
      int v = (X & 1) + 2 * dv;
      int qx = (X - v) >> 1;
      if (qx < 0 || qx >= ND) continue;
      acc += OPb[(size_t)(qy * ND + qx) * NJ + (c << 4) + (u << 2) + v];
    }
  }
  ob[id] = acc * (1.0f / 16.0f);
}

extern "C" void kernel_launch(void* const* d_in, const int* in_sizes, int n_in,
                              void* d_out, int out_size, void* d_ws, size_t ws_size,
                              hipStream_t stream) {
  const float* fg_all = (const float*)d_in[0];
  const float* bg_all = (const float*)d_in[1];
  const float* mask_all = (const float*)d_in[2];
  float* out_all = (float*)d_out;
  float* ws = (float*)d_ws;

  int B = in_sizes[0] / CHW;

  // per-sample sizes (elements)
  const size_t S_D = (size_t)CCH * LQ;      // 221184 f32
  const size_t S_P = LQ;                    // 2304  f32
  const size_t S_R = (size_t)LQ * LQ;       // 5308416 f32
  const size_t S_PBF = (size_t)LQ * LQ;     // 5308416 bf16
  const size_t S_W = (size_t)NJ * LQ;       // 3538944 bf16
  const size_t per_floats = S_D * 2 + S_P * 3 + S_R * 2 + S_PBF / 2 + S_W / 2; // 15489792

  bool batched = ws_size >= (size_t)B * per_floats * 4;
  int na = batched ? B : 1;   // allocation multiplier
  int nb = na;                // z-extent per launch

  float* fgdT  = ws;
  float* bgdT  = fgdT + (size_t)na * S_D;
  float* n2    = bgdT + (size_t)na * S_D;
  float* rnorm = n2 + (size_t)na * S_P;
  float* mval  = rnorm + (size_t)na * S_P;
  float* bufA  = mval + (size_t)na * S_P;              // R, A2, OP
  float* bufB  = bufA + (size_t)na * S_R;              // A1, F
  __hip_bfloat16* Pbf  = (__hip_bfloat16*)(bufB + (size_t)na * S_R);
  __hip_bfloat16* wrBT = Pbf + (size_t)na * S_PBF;

  size_t sd = batched ? S_D : 0, sp = batched ? S_P : 0, sR = batched ? S_R : 0;
  size_t sP = batched ? S_PBF : 0, sw = batched ? S_W : 0;

  for (int b0 = 0; b0 < B; b0 += nb) {
    const float* fg = fg_all + (size_t)(batched ? 0 : b0) * CHW;
    const float* bg = bg_all + (size_t)(batched ? 0 : b0) * CHW;
    const float* mask = mask_all + (size_t)(batched ? 0 : b0) * HW2;
    float* out = out_all + (size_t)(batched ? 0 : b0) * CHW;

    hipLaunchKernelGGL(k_down, dim3(9, 1, nb), dim3(256), 0, stream,
                       fg, bg, fgdT, bgdT, n2, sd, sp);
    hipLaunchKernelGGL(k_aux, dim3(9, 1, nb), dim3(256), 0, stream,
                       n2, mask, rnorm, mval, sp);
    hipLaunchKernelGGL(k_rgemm, dim3(36, 36, nb), dim3(256), 0, stream,
                       fgdT, bgdT, bufA, sd, sR);
    // separable T9 = T_row ∘ T_col, then flat T3:
    hipLaunchKernelGGL(k_tcol, dim3(20736, 1, nb), dim3(256), 0, stream,
                       bufA, bufB, sR);
    hipLaunchKernelGGL(k_trow, dim3(20736, 1, nb), dim3(256), 0, stream,
                       bufB, rnorm, bufA, sR, sp);
    hipLaunchKernelGGL(k_fuse, dim3(20736, 1, nb), dim3(256), 0, stream,
                       bufA, bufB, sR);
    hipLaunchKernelGGL(k_softmax, dim3(2304, 1, nb), dim3(256), 0, stream,
                       bufB, mval, Pbf, sR, sp, sP);
    hipLaunchKernelGGL(k_wrb, dim3(13824, 1, nb), dim3(256), 0, stream,
                       bg, wrBT, sw);
    hipLaunchKernelGGL(k_gemm2, dim3(12, 18, nb), dim3(256), 0, stream,
                       Pbf, wrBT, bufA, sP, sw, sR);
    hipLaunchKernelGGL(k_fold, dim3(3456, 1, nb), dim3(256), 0, stream,
                       bufA, out, sR);
  }
}

// Round 4
// 466.596 us; speedup vs baseline: 1.6299x; 1.0298x over previous
//
#include <hip/hip_runtime.h>
#include <hip/hip_bf16.h>
#include <cstdint>

#define ND 48
#define LQ 2304      // 48*48
#define CCH 96
#define HWD 96
#define CHW (CCH*HWD*HWD)   // 884736
#define HW2 (HWD*HWD)       // 9216
#define K2P 2560     // padded K (2500 = 50*50 live)
#define NJ2 384      // 96 ch * 4 (s,t)

typedef __attribute__((ext_vector_type(8))) short bf16x8;
typedef __attribute__((ext_vector_type(4))) float f32x4;

// ---------------- K0: downsample fg/bg to (c,p) layout + per-pos squared norm of bgd
__global__ void k_down(const float* __restrict__ fg, const float* __restrict__ bg,
                       float* __restrict__ fgdT, float* __restrict__ bgdT,
                       float* __restrict__ n2, size_t sd, size_t sp) {
  int b = blockIdx.z;
  const float* fgb = fg + (size_t)b * CHW;
  const float* bgb = bg + (size_t)b * CHW;
  float* fT = fgdT + (size_t)b * sd;
  float* bT = bgdT + (size_t)b * sd;
  float* n2b = n2 + (size_t)b * sp;
  int p = blockIdx.x * 256 + threadIdx.x;
  if (p >= LQ) return;
  int py = p / ND, px = p % ND;
  const float* fsrc = fgb + (2 * py) * HWD + 2 * px;
  const float* gsrc = bgb + (2 * py) * HWD + 2 * px;
  float s = 0.f;
  for (int c = 0; c < CCH; ++c) {
    float f = fsrc[c * HW2];
    float g = gsrc[c * HW2];
    fT[c * LQ + p] = f;
    bT[c * LQ + p] = g;
    s += g * g;
  }
  n2b[p] = s;
}

// ---------------- K0b: patch norms (rnorm) and mask means (mval)
__global__ void k_aux(const float* __restrict__ n2, const float* __restrict__ mask,
                      float* __restrict__ rnorm, float* __restrict__ mval, size_t sp) {
  int b = blockIdx.z;
  const float* n2b = n2 + (size_t)b * sp;
  const float* mb = mask + (size_t)b * HW2;
  float* rn = rnorm + (size_t)b * sp;
  float* mv = mval + (size_t)b * sp;
  int p = blockIdx.x * 256 + threadIdx.x;
  if (p >= LQ) return;
  int py = p / ND, px = p % ND;
  float ssq = 0.f, ms = 0.f;
  for (int dy = -1; dy <= 1; ++dy)
    for (int dx = -1; dx <= 1; ++dx) {
      int yy = py + dy, xx = px + dx;
      if (yy >= 0 && yy < ND && xx >= 0 && xx < ND) {
        ssq += n2b[yy * ND + xx];
        ms  += mb[(2 * yy) * HWD + 2 * xx];
      }
    }
  rn[p] = 1.0f / sqrtf(ssq + 864.0f * 1e-9f);
  mv[p] = ms * (1.0f / 9.0f);
}

// ---------------- K1: R[q][l] = sum_c fgdT[c][q] * bgdT[c][l]   (fp32, K=96)
__global__ __launch_bounds__(256) void k_rgemm(const float* __restrict__ fgdT,
                                               const float* __restrict__ bgdT,
                                               float* __restrict__ R,
                                               size_t sd, size_t sR) {
  int b = blockIdx.z;
  const float* fT = fgdT + (size_t)b * sd;
  const float* bT = bgdT + (size_t)b * sd;
  float* Rb = R + (size_t)b * sR;
  __shared__ float As[16][64];
  __shared__ float Bs[16][64];
  int l0 = blockIdx.x * 64, q0 = blockIdx.y * 64;
  int tid = threadIdx.x;
  int ty = tid / 16, tx = tid % 16;
  float acc[4][4] = {};
  for (int k0 = 0; k0 < CCH; k0 += 16) {
#pragma unroll
    for (int i = 0; i < 4; ++i) {
      int idx = tid + i * 256;
      int kk = idx >> 6, cc = idx & 63;
      As[kk][cc] = fT[(k0 + kk) * LQ + q0 + cc];
      Bs[kk][cc] = bT[(k0 + kk) * LQ + l0 + cc];
    }
    __syncthreads();
#pragma unroll
    for (int kk = 0; kk < 16; ++kk) {
      float a[4], bb[4];
#pragma unroll
      for (int i = 0; i < 4; ++i) a[i] = As[kk][ty * 4 + i];
#pragma unroll
      for (int j = 0; j < 4; ++j) bb[j] = Bs[kk][tx * 4 + j];
#pragma unroll
      for (int i = 0; i < 4; ++i)
#pragma unroll
        for (int j = 0; j < 4; ++j) acc[i][j] += a[i] * bb[j];
    }
    __syncthreads();
  }
#pragma unroll
  for (int i = 0; i < 4; ++i) {
    float4 v = make_float4(acc[i][0], acc[i][1], acc[i][2], acc[i][3]);
    *(float4*)&Rb[(size_t)(q0 + ty * 4 + i) * LQ + l0 + tx * 4] = v;
  }
}

// ---------------- K2a: T_col — A1[q][l] = sum_{dx in {-1,0,1}} R[q+dx][l+dx], x-coord masks
__global__ void k_tcol(const float* __restrict__ R, float* __restrict__ A1, size_t sR) {
  int b = blockIdx.z;
  const float* S = R + (size_t)b * sR;
  float* O = A1 + (size_t)b * sR;
  int id = blockIdx.x * 256 + threadIdx.x;
  int q = id / LQ, l = id % LQ;
  int qx = q % ND, lx = l % ND;
  float v = S[id];
  if (qx > 0 && lx > 0)            v += S[id - LQ - 1];
  if (qx < ND - 1 && lx < ND - 1)  v += S[id + LQ + 1];
  O[id] = v;
}

// ---------------- K2b: T_row (+rnorm) — A2[q][l] = rnorm[l]*sum_{dy} A1[q+48dy][l+48dy]
__global__ void k_trow(const float* __restrict__ A1, const float* __restrict__ rnorm,
                       float* __restrict__ A2, size_t sR, size_t sp) {
  int b = blockIdx.z;
  const float* S = A1 + (size_t)b * sR;
  const float* rn = rnorm + (size_t)b * sp;
  float* O = A2 + (size_t)b * sR;
  int id = blockIdx.x * 256 + threadIdx.x;
  int q = id / LQ, l = id % LQ;
  int qy = q / ND, ly = l / ND;
  const int OFF = ND * (LQ + 1);
  float v = S[id];
  if (qy > 0 && ly > 0)            v += S[id - OFF];
  if (qy < ND - 1 && ly < ND - 1)  v += S[id + OFF];
  O[id] = v * rn[l];
}

// ---------------- K2c: flat diag fuse — F[a][b] = sum_{d1} A2[a+d1][b+d1], flat bounds
__global__ void k_fuse(const float* __restrict__ simT, float* __restrict__ F, size_t sR) {
  int b = blockIdx.z;
  const float* S = simT + (size_t)b * sR;
  float* Fo = F + (size_t)b * sR;
  int id = blockIdx.x * 256 + threadIdx.x;
  int a = id / LQ, bc = id % LQ;
  float v = S[id];
  if (a > 0 && bc > 0)            v += S[id - LQ - 1];
  if (a < LQ - 1 && bc < LQ - 1)  v += S[id + LQ + 1];
  Fo[id] = v;
}

// ---------------- K3: second fuse (3 scattered taps) + masked softmax over l, write P bf16
__global__ __launch_bounds__(256) void k_softmax(const float* __restrict__ F,
                                                 const float* __restrict__ mval,
                                                 __hip_bfloat16* __restrict__ Pbf,
                                                 size_t sR, size_t sp, size_t sP) {
  int b = blockIdx.z;
  const float* Fb = F + (size_t)b * sR;
  const float* mv = mval + (size_t)b * sp;
  __hip_bfloat16* Pb = Pbf + (size_t)b * sP;
  int q = blockIdx.x;
  int qy = q / ND, qx = q % ND;
  int tid = threadIdx.x;
  __shared__ float red[256];
  int gqv[3]; bool qok[3];
#pragma unroll
  for (int t = 0; t < 3; ++t) {
    int fq = qx * ND + qy + (t - 1);
    qok[t] = (fq >= 0 && fq < LQ);
    gqv[t] = qok[t] ? (fq % ND) * ND + fq / ND : 0;
  }
  float logit[9];
  float vmax = -1e30f;
#pragma unroll
  for (int s = 0; s < 9; ++s) {
    int l = tid + s * 256;
    int ly = l / ND, lx = l % ND;
    float v = 0.f;
#pragma unroll
    for (int t = 0; t < 3; ++t) {
      if (!qok[t]) continue;
      int fl = lx * ND + ly + (t - 1);
      if (fl < 0 || fl >= LQ) continue;
      int gl = (fl % ND) * ND + fl / ND;
      v += Fb[(size_t)gqv[t] * LQ + gl];
    }
    float lg = v * (10.0f * mv[l]);
    logit[s] = lg;
    vmax = fmaxf(vmax, lg);
  }
  red[tid] = vmax;
  __syncthreads();
  for (int w = 128; w > 0; w >>= 1) {
    if (tid < w) red[tid] = fmaxf(red[tid], red[tid + w]);
    __syncthreads();
  }
  float m = red[0];
  __syncthreads();
  float e[9], ssum = 0.f;
#pragma unroll
  for (int s = 0; s < 9; ++s) { e[s] = __expf(logit[s] - m); ssum += e[s]; }
  red[tid] = ssum;
  __syncthreads();
  for (int w = 128; w > 0; w >>= 1) {
    if (tid < w) red[tid] += red[tid + w];
    __syncthreads();
  }
  float inv = 1.0f / red[0];
#pragma unroll
  for (int s = 0; s < 9; ++s) {
    int l = tid + s * 256;
    float p = e[s] * inv * mv[l];
    Pb[(size_t)q * LQ + l] = __float2bfloat16(p);
  }
}

// ---------------- K4a: Q2[(a,b),(m,n)] = sum_{du,dv} P[(a-du,b-dv),(m-2du,n-2dv)]
__global__ void k_q2(const __hip_bfloat16* __restrict__ P, __hip_bfloat16* __restrict__ Q2,
                     size_t sP, size_t sQ) {
  int b = blockIdx.z;
  const __hip_bfloat16* Pb = P + (size_t)b * sP;
  __hip_bfloat16* Qb = Q2 + (size_t)b * sQ;
  int id = blockIdx.x * 256 + threadIdx.x;   // over 2304*2560
  int r = id / K2P, col = id % K2P;
  float v = 0.f;
  if (col < 2500) {
    int m = col / 50, n = col % 50;
    int a = r / ND, bb = r % ND;
#pragma unroll
    for (int du = 0; du <= 1; ++du) {
      int mm = m - 2 * du;
      if (a - du < 0 || mm < 0 || mm >= ND) continue;
#pragma unroll
      for (int dv = 0; dv <= 1; ++dv) {
        int nn = n - 2 * dv;
        if (bb - dv < 0 || nn < 0 || nn >= ND) continue;
        v += __bfloat162float(Pb[(size_t)(r - ND * du - dv) * LQ + mm * ND + nn]);
      }
    }
  }
  Qb[id] = __float2bfloat16(v);
}

// ---------------- K4b: B2[(c,s,t),(m,n)] = bgd[c, m+s-1, n+t-1] (zero-padded)
__global__ void k_b2(const float* __restrict__ bgdT, __hip_bfloat16* __restrict__ B2,
                     size_t sd, size_t sB) {
  int b = blockIdx.z;
  const float* gT = bgdT + (size_t)b * sd;
  __hip_bfloat16* Bb = B2 + (size_t)b * sB;
  int id = blockIdx.x * 256 + threadIdx.x;   // over 384*2560
  if (id >= NJ2 * K2P) return;
  int j = id / K2P, col = id % K2P;
  int c = j >> 2, s = (j >> 1) & 1, t = j & 1;
  float v = 0.f;
  if (col < 2500) {
    int m = col / 50, n = col % 50;
    int ry = m + s - 1, rx = n + t - 1;
    if (ry >= 0 && ry < ND && rx >= 0 && rx < ND)
      v = gT[c * LQ + ry * ND + rx];
  }
  Bb[id] = __float2bfloat16(v);
}

// ---------------- K5: bf16 MFMA GEMM: out = (1/16) * Q2 @ B2^T, direct interleaved store
__device__ __forceinline__ void gload16(const void* g, void* l) {
  __builtin_amdgcn_global_load_lds((const __attribute__((address_space(1))) void*)g,
                                   (__attribute__((address_space(3))) void*)l, 16, 0, 0);
}

__global__ __launch_bounds__(256) void k_gemm3(const __hip_bfloat16* __restrict__ A,
                                               const __hip_bfloat16* __restrict__ B,
                                               float* __restrict__ out,
                                               size_t sQ, size_t sB) {
  int bz = blockIdx.z;
  const __hip_bfloat16* Ab = A + (size_t)bz * sQ;
  const __hip_bfloat16* Bb = B + (size_t)bz * sB;
  float* ob = out + (size_t)bz * CHW;
  __shared__ __align__(16) __hip_bfloat16 As[2][128 * 64];
  __shared__ __align__(16) __hip_bfloat16 Bs[2][128 * 64];
  int m0 = blockIdx.y * 128, n0 = blockIdx.x * 128;
  int tid = threadIdx.x;
  int w = tid >> 6, lane = tid & 63;
  int wm = w >> 1, wn = w & 1;
  f32x4 acc[4][4] = {};

  auto STAGE = [&](int buf, int k0) {
#pragma unroll
    for (int i = 0; i < 4; ++i) {
      int chunk = w * 4 + i;                 // 16 chunks x 8 rows = 128 rows
      int row = chunk * 8 + (lane >> 3);
      int kc = k0 + (lane & 7) * 8;
      gload16(Ab + (size_t)(m0 + row) * K2P + kc, &As[buf][chunk * 8 * 64]);
      gload16(Bb + (size_t)(n0 + row) * K2P + kc, &Bs[buf][chunk * 8 * 64]);
    }
  };

  STAGE(0, 0);
  __syncthreads();          // drains vmcnt (compiler emits full waitcnt before barrier)
  int cur = 0;
  constexpr int NT = K2P / 64;   // 40
  for (int t = 0; t < NT; ++t) {
    if (t + 1 < NT) STAGE(cur ^ 1, (t + 1) * 64);   // prefetch overlaps compute
#pragma unroll
    for (int kk = 0; kk < 64; kk += 32) {
      bf16x8 af[4], bfr[4];
#pragma unroll
      for (int mi = 0; mi < 4; ++mi)
        af[mi] = *(const bf16x8*)(&As[cur][(wm * 64 + mi * 16 + (lane & 15)) * 64 + kk + (lane >> 4) * 8]);
#pragma unroll
      for (int ni = 0; ni < 4; ++ni)
        bfr[ni] = *(const bf16x8*)(&Bs[cur][(wn * 64 + ni * 16 + (lane & 15)) * 64 + kk + (lane >> 4) * 8]);
#pragma unroll
      for (int mi = 0; mi < 4; ++mi)
#pragma unroll
        for (int ni = 0; ni < 4; ++ni)
          acc[mi][ni] = __builtin_amdgcn_mfma_f32_16x16x32_bf16(af[mi], bfr[ni], acc[mi][ni], 0, 0, 0);
    }
    __syncthreads();        // next buffer staged + all readers done with cur
    cur ^= 1;
  }

#pragma unroll
  for (int mi = 0; mi < 4; ++mi)
#pragma unroll
    for (int ni = 0; ni < 4; ++ni)
#pragma unroll
      for (int rr = 0; rr < 4; ++rr) {
        int r_ = m0 + wm * 64 + mi * 16 + (lane >> 4) * 4 + rr;  // M row = a*48+b
        int j  = n0 + wn * 64 + ni * 16 + (lane & 15);           // N col = c*4+s*2+t
        int a = r_ / ND, bcol = r_ % ND;
        int c = j >> 2, s = (j >> 1) & 1, tt = j & 1;
        ob[((size_t)c * HWD + 2 * a + s) * HWD + 2 * bcol + tt] = acc[mi][ni][rr] * 0.0625f;
      }
}

extern "C" void kernel_launch(void* const* d_in, const int* in_sizes, int n_in,
                              void* d_out, int out_size, void* d_ws, size_t ws_size,
                              hipStream_t stream) {
  const float* fg_all = (const float*)d_in[0];
  const float* bg_all = (const float*)d_in[1];
  const float* mask_all = (const float*)d_in[2];
  float* out_all = (float*)d_out;
  float* ws = (float*)d_ws;

  int B = in_sizes[0] / CHW;

  // per-sample sizes (elements)
  const size_t S_D = (size_t)CCH * LQ;      // 221184 f32
  const size_t S_P = LQ;                    // 2304  f32
  const size_t S_R = (size_t)LQ * LQ;       // 5308416 f32
  const size_t S_PBF = (size_t)LQ * LQ;     // 5308416 bf16
  // Q2 (2304*2560 bf16 = 2949120 f32-equiv) and B2 (384*2560 bf16) overlay bufA/bufB
  const size_t per_floats = S_D * 2 + S_P * 3 + S_R * 2 + S_PBF / 2; // 13720320

  bool batched = ws_size >= (size_t)B * per_floats * 4;
  int na = batched ? B : 1;
  int nb = na;

  float* fgdT  = ws;
  float* bgdT  = fgdT + (size_t)na * S_D;
  float* n2    = bgdT + (size_t)na * S_D;
  float* rnorm = n2 + (size_t)na * S_P;
  float* mval  = rnorm + (size_t)na * S_P;
  float* bufA  = mval + (size_t)na * S_P;              // R, A2, then Q2 (bf16 overlay)
  float* bufB  = bufA + (size_t)na * S_R;              // A1, F, then B2 (bf16 overlay)
  __hip_bfloat16* Pbf = (__hip_bfloat16*)(bufB + (size_t)na * S_R);
  __hip_bfloat16* Q2  = (__hip_bfloat16*)bufA;         // 2304*2560 bf16 per z (fits in S_R)
  __hip_bfloat16* B2  = (__hip_bfloat16*)bufB;         // 384*2560 bf16 per z

  size_t sd = batched ? S_D : 0, sp = batched ? S_P : 0, sR = batched ? S_R : 0;
  size_t sP = batched ? S_PBF : 0;
  size_t sQ = batched ? S_R * 2 : 0;   // bf16 slots per z within bufA
  size_t sB = batched ? S_R * 2 : 0;   // bf16 slots per z within bufB

  for (int b0 = 0; b0 < B; b0 += nb) {
    const float* fg = fg_all + (size_t)(batched ? 0 : b0) * CHW;
    const float* bg = bg_all + (size_t)(batched ? 0 : b0) * CHW;
    const float* mask = mask_all + (size_t)(batched ? 0 : b0) * HW2;
    float* out = out_all + (size_t)(batched ? 0 : b0) * CHW;

    hipLaunchKernelGGL(k_down, dim3(9, 1, nb), dim3(256), 0, stream,
                       fg, bg, fgdT, bgdT, n2, sd, sp);
    hipLaunchKernelGGL(k_aux, dim3(9, 1, nb), dim3(256), 0, stream,
                       n2, mask, rnorm, mval, sp);
    hipLaunchKernelGGL(k_rgemm, dim3(36, 36, nb), dim3(256), 0, stream,
                       fgdT, bgdT, bufA, sd, sR);
    hipLaunchKernelGGL(k_tcol, dim3(20736, 1, nb), dim3(256), 0, stream,
                       bufA, bufB, sR);
    hipLaunchKernelGGL(k_trow, dim3(20736, 1, nb), dim3(256), 0, stream,
                       bufB, rnorm, bufA, sR, sp);
    hipLaunchKernelGGL(k_fuse, dim3(20736, 1, nb), dim3(256), 0, stream,
                       bufA, bufB, sR);
    hipLaunchKernelGGL(k_softmax, dim3(2304, 1, nb), dim3(256), 0, stream,
                       bufB, mval, Pbf, sR, sp, sP);
    // Q2 pre-fuse (bufA now dead -> reuse as Q2), B2 build (bufB dead -> reuse)
    hipLaunchKernelGGL(k_q2, dim3(23040, 1, nb), dim3(256), 0, stream,
                       Pbf, Q2, sP, sQ);
    hipLaunchKernelGGL(k_b2, dim3(3840, 1, nb), dim3(256), 0, stream,
                       bgdT, B2, sd, sB);
    hipLaunchKernelGGL(k_gemm3, dim3(3, 18, nb), dim3(256), 0, stream,
                       Q2, B2, out, sQ, sB);
  }
}

// Round 5
// 387.821 us; speedup vs baseline: 1.9610x; 1.2031x over previous
//
#include <hip/hip_runtime.h>
#include <hip/hip_bf16.h>
#include <cstdint>

#define ND 48
#define LQ 2304      // 48*48
#define CCH 96
#define HWD 96
#define CHW (CCH*HWD*HWD)   // 884736
#define HW2 (HWD*HWD)       // 9216
#define K2P 2560     // padded K (50-grid: 2500 live, cols>=2500 zero)
#define NJ2 384      // 96 ch * 4 (s,t)

typedef __attribute__((ext_vector_type(8))) short bf16x8;
typedef __attribute__((ext_vector_type(4))) float f32x4;

__device__ __forceinline__ float4 ld4u(const float* p) {  // 4B-aligned float4 load
  float4 v; __builtin_memcpy(&v, p, 16); return v;
}

// ---------------- K0: downsample fg/bg to (c,p) layout + per-pos squared norm of bgd
__global__ void k_down(const float* __restrict__ fg, const float* __restrict__ bg,
                       float* __restrict__ fgdT, float* __restrict__ bgdT,
                       float* __restrict__ n2, size_t sd, size_t sp) {
  int b = blockIdx.z;
  const float* fgb = fg + (size_t)b * CHW;
  const float* bgb = bg + (size_t)b * CHW;
  float* fT = fgdT + (size_t)b * sd;
  float* bT = bgdT + (size_t)b * sd;
  float* n2b = n2 + (size_t)b * sp;
  int p = blockIdx.x * 256 + threadIdx.x;
  if (p >= LQ) return;
  int py = p / ND, px = p % ND;
  const float* fsrc = fgb + (2 * py) * HWD + 2 * px;
  const float* gsrc = bgb + (2 * py) * HWD + 2 * px;
  float s = 0.f;
  for (int c = 0; c < CCH; ++c) {
    float f = fsrc[c * HW2];
    float g = gsrc[c * HW2];
    fT[c * LQ + p] = f;
    bT[c * LQ + p] = g;
    s += g * g;
  }
  n2b[p] = s;
}

// ---------------- K0b: patch norms (rnorm) and mask means (mval)
__global__ void k_aux(const float* __restrict__ n2, const float* __restrict__ mask,
                      float* __restrict__ rnorm, float* __restrict__ mval, size_t sp) {
  int b = blockIdx.z;
  const float* n2b = n2 + (size_t)b * sp;
  const float* mb = mask + (size_t)b * HW2;
  float* rn = rnorm + (size_t)b * sp;
  float* mv = mval + (size_t)b * sp;
  int p = blockIdx.x * 256 + threadIdx.x;
  if (p >= LQ) return;
  int py = p / ND, px = p % ND;
  float ssq = 0.f, ms = 0.f;
  for (int dy = -1; dy <= 1; ++dy)
    for (int dx = -1; dx <= 1; ++dx) {
      int yy = py + dy, xx = px + dx;
      if (yy >= 0 && yy < ND && xx >= 0 && xx < ND) {
        ssq += n2b[yy * ND + xx];
        ms  += mb[(2 * yy) * HWD + 2 * xx];
      }
    }
  rn[p] = 1.0f / sqrtf(ssq + 864.0f * 1e-9f);
  mv[p] = ms * (1.0f / 9.0f);
}

// ---------------- K1: R[q][l] = sum_c fgdT[c][q] * bgdT[c][l]   (fp32, K=96)
__global__ __launch_bounds__(256) void k_rgemm(const float* __restrict__ fgdT,
                                               const float* __restrict__ bgdT,
                                               float* __restrict__ R,
                                               size_t sd, size_t sR) {
  int b = blockIdx.z;
  const float* fT = fgdT + (size_t)b * sd;
  const float* bT = bgdT + (size_t)b * sd;
  float* Rb = R + (size_t)b * sR;
  __shared__ float As[16][64];
  __shared__ float Bs[16][64];
  int l0 = blockIdx.x * 64, q0 = blockIdx.y * 64;
  int tid = threadIdx.x;
  int ty = tid / 16, tx = tid % 16;
  float acc[4][4] = {};
  for (int k0 = 0; k0 < CCH; k0 += 16) {
#pragma unroll
    for (int i = 0; i < 4; ++i) {
      int idx = tid + i * 256;
      int kk = idx >> 6, cc = idx & 63;
      As[kk][cc] = fT[(k0 + kk) * LQ + q0 + cc];
      Bs[kk][cc] = bT[(k0 + kk) * LQ + l0 + cc];
    }
    __syncthreads();
#pragma unroll
    for (int kk = 0; kk < 16; ++kk) {
      float a[4], bb[4];
#pragma unroll
      for (int i = 0; i < 4; ++i) a[i] = As[kk][ty * 4 + i];
#pragma unroll
      for (int j = 0; j < 4; ++j) bb[j] = Bs[kk][tx * 4 + j];
#pragma unroll
      for (int i = 0; i < 4; ++i)
#pragma unroll
        for (int j = 0; j < 4; ++j) acc[i][j] += a[i] * bb[j];
    }
    __syncthreads();
  }
#pragma unroll
  for (int i = 0; i < 4; ++i) {
    float4 v = make_float4(acc[i][0], acc[i][1], acc[i][2], acc[i][3]);
    *(float4*)&Rb[(size_t)(q0 + ty * 4 + i) * LQ + l0 + tx * 4] = v;
  }
}

// ---------------- K2a: T_col (vectorized) — A1 = 3-tap diag, masks on (qx,lx)
__global__ void k_tcolv(const float* __restrict__ R, float* __restrict__ A1, size_t sR) {
  int b = blockIdx.z;
  const float* S = R + (size_t)b * sR;
  float* O = A1 + (size_t)b * sR;
  int t = blockIdx.x * 256 + threadIdx.x;      // LQ*LQ/4 threads
  int id = t * 4;
  int q = id / LQ, l = id % LQ;
  int qx = q % ND, lx0 = l % ND;               // lx0 in {0,4,...,44}; same q for all 4
  float4 c = *(const float4*)(S + id);
  if (qx > 0) {
    float4 m = ld4u(S + id - LQ - 1);
    if (lx0 == 0) m.x = 0.f;
    c.x += m.x; c.y += m.y; c.z += m.z; c.w += m.w;
  }
  if (qx < ND - 1) {
    float4 p = ld4u(S + id + LQ + 1);
    if (lx0 == ND - 4) p.w = 0.f;
    c.x += p.x; c.y += p.y; c.z += p.z; c.w += p.w;
  }
  *(float4*)(O + id) = c;
}

// ---------------- K2b: T_row (+rnorm, vectorized) — masks on (qy,ly), aligned taps
__global__ void k_trowv(const float* __restrict__ A1, const float* __restrict__ rnorm,
                        float* __restrict__ A2, size_t sR, size_t sp) {
  int b = blockIdx.z;
  const float* S = A1 + (size_t)b * sR;
  const float* rn = rnorm + (size_t)b * sp;
  float* O = A2 + (size_t)b * sR;
  int t = blockIdx.x * 256 + threadIdx.x;
  int id = t * 4;
  int q = id / LQ, l = id % LQ;
  int qy = q / ND, ly = l / ND;                // uniform over the 4 elements
  const int OFF = ND * (LQ + 1);               // 110640, %4==0 -> aligned
  float4 c = *(const float4*)(S + id);
  if (qy > 0 && ly > 0) {
    float4 m = *(const float4*)(S + id - OFF);
    c.x += m.x; c.y += m.y; c.z += m.z; c.w += m.w;
  }
  if (qy < ND - 1 && ly < ND - 1) {
    float4 p = *(const float4*)(S + id + OFF);
    c.x += p.x; c.y += p.y; c.z += p.z; c.w += p.w;
  }
  float4 r4 = *(const float4*)(rn + l);
  c.x *= r4.x; c.y *= r4.y; c.z *= r4.z; c.w *= r4.w;
  *(float4*)(O + id) = c;
}

// ---------------- K2c: flat diag fuse (vectorized) — flat bounds on (a,bc)
__global__ void k_fusev(const float* __restrict__ A2, float* __restrict__ F, size_t sR) {
  int b = blockIdx.z;
  const float* S = A2 + (size_t)b * sR;
  float* Fo = F + (size_t)b * sR;
  int t = blockIdx.x * 256 + threadIdx.x;
  int id = t * 4;
  int a = id / LQ, bc0 = id % LQ;
  float4 c = *(const float4*)(S + id);
  if (a > 0) {
    float4 m = ld4u(S + id - LQ - 1);
    if (bc0 == 0) m.x = 0.f;
    c.x += m.x; c.y += m.y; c.z += m.z; c.w += m.w;
  }
  if (a < LQ - 1) {
    float4 p = ld4u(S + id + LQ + 1);
    if (bc0 == LQ - 4) p.w = 0.f;
    c.x += p.x; c.y += p.y; c.z += p.z; c.w += p.w;
  }
  *(float4*)(Fo + id) = c;
}

// ---------------- K3: second fuse (3 taps) + masked softmax over l, write P50 (bf16)
// P50 layout: [guard row 2560][2304 rows x 2560]; col = ly*50+lx; pads zeroed.
__global__ __launch_bounds__(256) void k_softmax(const float* __restrict__ F,
                                                 const float* __restrict__ mval,
                                                 __hip_bfloat16* __restrict__ P50s,
                                                 size_t sR, size_t sp, size_t sP) {
  int b = blockIdx.z;
  const float* Fb = F + (size_t)b * sR;
  const float* mv = mval + (size_t)b * sp;
  __hip_bfloat16* Pb = P50s + (size_t)b * sP + K2P;   // skip guard row
  int q = blockIdx.x;
  int qy = q / ND, qx = q % ND;
  int tid = threadIdx.x;
  __shared__ float red[256];
  int gqv[3]; bool qok[3];
#pragma unroll
  for (int t = 0; t < 3; ++t) {
    int fq = qx * ND + qy + (t - 1);
    qok[t] = (fq >= 0 && fq < LQ);
    gqv[t] = qok[t] ? (fq % ND) * ND + fq / ND : 0;
  }
  float logit[9];
  float vmax = -1e30f;
#pragma unroll
  for (int s = 0; s < 9; ++s) {
    int l = tid + s * 256;
    int ly = l / ND, lx = l % ND;
    float v = 0.f;
#pragma unroll
    for (int t = 0; t < 3; ++t) {
      if (!qok[t]) continue;
      int fl = lx * ND + ly + (t - 1);
      if (fl < 0 || fl >= LQ) continue;
      int gl = (fl % ND) * ND + fl / ND;
      v += Fb[(size_t)gqv[t] * LQ + gl];
    }
    float lg = v * (10.0f * mv[l]);
    logit[s] = lg;
    vmax = fmaxf(vmax, lg);
  }
  red[tid] = vmax;
  __syncthreads();
  for (int w = 128; w > 0; w >>= 1) {
    if (tid < w) red[tid] = fmaxf(red[tid], red[tid + w]);
    __syncthreads();
  }
  float m = red[0];
  __syncthreads();
  float e[9], ssum = 0.f;
#pragma unroll
  for (int s = 0; s < 9; ++s) { e[s] = __expf(logit[s] - m); ssum += e[s]; }
  red[tid] = ssum;
  __syncthreads();
  for (int w = 128; w > 0; w >>= 1) {
    if (tid < w) red[tid] += red[tid + w];
    __syncthreads();
  }
  float inv = 1.0f / red[0];
  __hip_bfloat16 z = __float2bfloat16(0.f);
#pragma unroll
  for (int s = 0; s < 9; ++s) {
    int l = tid + s * 256;
    float p = e[s] * inv * mv[l];
    int col = (l / ND) * 50 + (l % ND);
    Pb[(size_t)q * K2P + col] = __float2bfloat16(p);
  }
  // zero this row's 256 pad columns
  int pc;
  if (tid < 96)        pc = (tid >> 1) * 50 + ND + (tid & 1);   // (m<48, n in {48,49})
  else if (tid < 196)  pc = 2400 + (tid - 96);                  // m in {48,49}
  else                 pc = 2500 + (tid - 196);                 // tail
  Pb[(size_t)q * K2P + pc] = z;
  // block 0 zeroes the guard row (absorbs stencil underflow <= 102 elems)
  if (q == 0)
    for (int i = tid; i < K2P; i += 256) (Pb - K2P)[i] = z;
}

// ---------------- K4a: Q2 = 4-flat-tap stencil of P50 (vectorized, bit-identical order)
__global__ void k_q2v(const __hip_bfloat16* __restrict__ P50s,
                      __hip_bfloat16* __restrict__ Q2, size_t sP, size_t sQ) {
  int bz = blockIdx.z;
  const __hip_bfloat16* P = P50s + (size_t)bz * sP + K2P;
  __hip_bfloat16* Q = Q2 + (size_t)bz * sQ;
  int id = blockIdx.x * 256 + threadIdx.x;     // 2304*320 threads
  int r = id / 320, c8 = (id % 320) * 8;
  int a = r / ND, b = r % ND;
  const __hip_bfloat16* base = P + (size_t)r * K2P + c8;
  float acc[8];
  {  // tap (0,0) — aligned
    unsigned short s[8]; __builtin_memcpy(s, base, 16);
#pragma unroll
    for (int i = 0; i < 8; ++i) {
      unsigned int u = ((unsigned int)s[i]) << 16;
      acc[i] = __builtin_bit_cast(float, u);
    }
  }
  if (b >= 1) {   // tap (du=0,dv=1): offset -(K2P + 2)
    unsigned short s[8]; __builtin_memcpy(s, base - (K2P + 2), 16);
#pragma unroll
    for (int i = 0; i < 8; ++i) {
      unsigned int u = ((unsigned int)s[i]) << 16;
      acc[i] += __builtin_bit_cast(float, u);
    }
  }
  if (a >= 1) {   // tap (du=1,dv=0): offset -(48*K2P + 100)
    unsigned short s[8]; __builtin_memcpy(s, base - (ND * K2P + 100), 16);
#pragma unroll
    for (int i = 0; i < 8; ++i) {
      unsigned int u = ((unsigned int)s[i]) << 16;
      acc[i] += __builtin_bit_cast(float, u);
    }
  }
  if (a >= 1 && b >= 1) {   // tap (du=1,dv=1): offset -(49*K2P + 102)
    unsigned short s[8]; __builtin_memcpy(s, base - ((ND + 1) * K2P + 102), 16);
#pragma unroll
    for (int i = 0; i < 8; ++i) {
      unsigned int u = ((unsigned int)s[i]) << 16;
      acc[i] += __builtin_bit_cast(float, u);
    }
  }
  __hip_bfloat16 o[8];
#pragma unroll
  for (int i = 0; i < 8; ++i) o[i] = __float2bfloat16(acc[i]);
  *(bf16x8*)(Q + (size_t)r * K2P + c8) = *(bf16x8*)o;
}

// ---------------- K4b: B2[(c,s,t),(m,n)] = bgd[c, m+s-1, n+t-1] (zero-padded)
__global__ void k_b2(const float* __restrict__ bgdT, __hip_bfloat16* __restrict__ B2,
                     size_t sd, size_t sB) {
  int b = blockIdx.z;
  const float* gT = bgdT + (size_t)b * sd;
  __hip_bfloat16* Bb = B2 + (size_t)b * sB;
  int id = blockIdx.x * 256 + threadIdx.x;   // over 384*2560
  if (id >= NJ2 * K2P) return;
  int j = id / K2P, col = id % K2P;
  int c = j >> 2, s = (j >> 1) & 1, t = j & 1;
  float v = 0.f;
  if (col < 2500) {
    int m = col / 50, n = col % 50;
    int ry = m + s - 1, rx = n + t - 1;
    if (ry >= 0 && ry < ND && rx >= 0 && rx < ND)
      v = gT[c * LQ + ry * ND + rx];
  }
  Bb[id] = __float2bfloat16(v);
}

// ---------------- K5: bf16 MFMA GEMM: out = (1/16) * Q2 @ B2^T, direct interleaved store
__device__ __forceinline__ void gload16(const void* g, void* l) {
  __builtin_amdgcn_global_load_lds((const __attribute__((address_space(1))) void*)g,
                                   (__attribute__((address_space(3))) void*)l, 16, 0, 0);
}

__global__ __launch_bounds__(256) void k_gemm3(const __hip_bfloat16* __restrict__ A,
                                               const __hip_bfloat16* __restrict__ B,
                                               float* __restrict__ out,
                                               size_t sQ, size_t sB) {
  int bz = blockIdx.z;
  const __hip_bfloat16* Ab = A + (size_t)bz * sQ;
  const __hip_bfloat16* Bb = B + (size_t)bz * sB;
  float* ob = out + (size_t)bz * CHW;
  __shared__ __align__(16) __hip_bfloat16 As[2][128 * 64];
  __shared__ __align__(16) __hip_bfloat16 Bs[2][128 * 64];
  int m0 = blockIdx.y * 128, n0 = blockIdx.x * 128;
  int tid = threadIdx.x;
  int w = tid >> 6, lane = tid & 63;
  int wm = w >> 1, wn = w & 1;
  f32x4 acc[4][4] = {};

  auto STAGE = [&](int buf, int k0) {
#pragma unroll
    for (int i = 0; i < 4; ++i) {
      int chunk = w * 4 + i;
      int row = chunk * 8 + (lane >> 3);
      int kc = k0 + (lane & 7) * 8;
      gload16(Ab + (size_t)(m0 + row) * K2P + kc, &As[buf][chunk * 8 * 64]);
      gload16(Bb + (size_t)(n0 + row) * K2P + kc, &Bs[buf][chunk * 8 * 64]);
    }
  };

  STAGE(0, 0);
  __syncthreads();
  int cur = 0;
  constexpr int NT = K2P / 64;   // 40
  for (int t = 0; t < NT; ++t) {
    if (t + 1 < NT) STAGE(cur ^ 1, (t + 1) * 64);
#pragma unroll
    for (int kk = 0; kk < 64; kk += 32) {
      bf16x8 af[4], bfr[4];
#pragma unroll
      for (int mi = 0; mi < 4; ++mi)
        af[mi] = *(const bf16x8*)(&As[cur][(wm * 64 + mi * 16 + (lane & 15)) * 64 + kk + (lane >> 4) * 8]);
#pragma unroll
      for (int ni = 0; ni < 4; ++ni)
        bfr[ni] = *(const bf16x8*)(&Bs[cur][(wn * 64 + ni * 16 + (lane & 15)) * 64 + kk + (lane >> 4) * 8]);
#pragma unroll
      for (int mi = 0; mi < 4; ++mi)
#pragma unroll
        for (int ni = 0; ni < 4; ++ni)
          acc[mi][ni] = __builtin_amdgcn_mfma_f32_16x16x32_bf16(af[mi], bfr[ni], acc[mi][ni], 0, 0, 0);
    }
    __syncthreads();
    cur ^= 1;
  }

#pragma unroll
  for (int mi = 0; mi < 4; ++mi)
#pragma unroll
    for (int ni = 0; ni < 4; ++ni)
#pragma unroll
      for (int rr = 0; rr < 4; ++rr) {
        int r_ = m0 + wm * 64 + mi * 16 + (lane >> 4) * 4 + rr;  // M row = a*48+b
        int j  = n0 + wn * 64 + ni * 16 + (lane & 15);           // N col = c*4+s*2+t
        int a = r_ / ND, bcol = r_ % ND;
        int c = j >> 2, s = (j >> 1) & 1, tt = j & 1;
        ob[((size_t)c * HWD + 2 * a + s) * HWD + 2 * bcol + tt] = acc[mi][ni][rr] * 0.0625f;
      }
}

extern "C" void kernel_launch(void* const* d_in, const int* in_sizes, int n_in,
                              void* d_out, int out_size, void* d_ws, size_t ws_size,
                              hipStream_t stream) {
  const float* fg_all = (const float*)d_in[0];
  const float* bg_all = (const float*)d_in[1];
  const float* mask_all = (const float*)d_in[2];
  float* out_all = (float*)d_out;
  float* ws = (float*)d_ws;

  int B = in_sizes[0] / CHW;

  const size_t S_D = (size_t)CCH * LQ;            // 221184 f32
  const size_t S_P = LQ;                          // 2304 f32
  const size_t S_R = (size_t)LQ * LQ;             // 5308416 f32
  const size_t S_P50 = (size_t)(LQ + 1) * K2P;    // 5900800 bf16 (incl guard row)
  const size_t per_floats = S_D * 2 + S_P * 3 + S_R * 2 + S_P50 / 2; // 14016512

  bool batched = ws_size >= (size_t)B * per_floats * 4;
  int na = batched ? B : 1;
  int nb = na;

  float* fgdT  = ws;
  float* bgdT  = fgdT + (size_t)na * S_D;
  float* n2    = bgdT + (size_t)na * S_D;
  float* rnorm = n2 + (size_t)na * S_P;
  float* mval  = rnorm + (size_t)na * S_P;
  float* bufA  = mval + (size_t)na * S_P;              // R, A2, then Q2 (bf16 overlay)
  float* bufB  = bufA + (size_t)na * S_R;              // A1, F, then B2 (bf16 overlay)
  __hip_bfloat16* P50 = (__hip_bfloat16*)(bufB + (size_t)na * S_R);
  __hip_bfloat16* Q2  = (__hip_bfloat16*)bufA;         // 2304*2560 bf16 fits in S_R
  __hip_bfloat16* B2  = (__hip_bfloat16*)bufB;

  size_t sd = batched ? S_D : 0, sp = batched ? S_P : 0, sR = batched ? S_R : 0;
  size_t sP = batched ? S_P50 : 0;
  size_t sQ = batched ? S_R * 2 : 0;
  size_t sB = batched ? S_R * 2 : 0;

  for (int b0 = 0; b0 < B; b0 += nb) {
    const float* fg = fg_all + (size_t)(batched ? 0 : b0) * CHW;
    const float* bg = bg_all + (size_t)(batched ? 0 : b0) * CHW;
    const float* mask = mask_all + (size_t)(batched ? 0 : b0) * HW2;
    float* out = out_all + (size_t)(batched ? 0 : b0) * CHW;

    hipLaunchKernelGGL(k_down, dim3(9, 1, nb), dim3(256), 0, stream,
                       fg, bg, fgdT, bgdT, n2, sd, sp);
    hipLaunchKernelGGL(k_aux, dim3(9, 1, nb), dim3(256), 0, stream,
                       n2, mask, rnorm, mval, sp);
    hipLaunchKernelGGL(k_rgemm, dim3(36, 36, nb), dim3(256), 0, stream,
                       fgdT, bgdT, bufA, sd, sR);
    hipLaunchKernelGGL(k_tcolv, dim3(5184, 1, nb), dim3(256), 0, stream,
                       bufA, bufB, sR);
    hipLaunchKernelGGL(k_trowv, dim3(5184, 1, nb), dim3(256), 0, stream,
                       bufB, rnorm, bufA, sR, sp);
    hipLaunchKernelGGL(k_fusev, dim3(5184, 1, nb), dim3(256), 0, stream,
                       bufA, bufB, sR);
    hipLaunchKernelGGL(k_softmax, dim3(2304, 1, nb), dim3(256), 0, stream,
                       bufB, mval, P50, sR, sp, sP);
    hipLaunchKernelGGL(k_q2v, dim3(2880, 1, nb), dim3(256), 0, stream,
                       P50, Q2, sP, sQ);
    hipLaunchKernelGGL(k_b2, dim3(3840, 1, nb), dim3(256), 0, stream,
                       bgdT, B2, sd, sB);
    hipLaunchKernelGGL(k_gemm3, dim3(3, 18, nb), dim3(256), 0, stream,
                       Q2, B2, out, sQ, sB);
  }
}

// Round 6
// 356.113 us; speedup vs baseline: 2.1356x; 1.0890x over previous
//
#include <hip/hip_runtime.h>
#include <hip/hip_bf16.h>
#include <cstdint>

#define ND 48
#define LQ 2304      // 48*48
#define CCH 96
#define HWD 96
#define CHW (CCH*HWD*HWD)   // 884736
#define HW2 (HWD*HWD)       // 9216
#define K2P 2560     // padded K (50-grid: 2500 live, cols>=2500 zero)
#define NJ2 384      // 96 ch * 4 (s,t)

typedef __attribute__((ext_vector_type(8))) short bf16x8;
typedef __attribute__((ext_vector_type(4))) float f32x4;

__device__ __forceinline__ float4 ld4u(const float* p) {  // 4B-aligned float4 load
  float4 v; __builtin_memcpy(&v, p, 16); return v;
}

// ---------------- K0: downsample fg/bg to (c,p) layout + per-pos squared norm of bgd
__global__ void k_down(const float* __restrict__ fg, const float* __restrict__ bg,
                       float* __restrict__ fgdT, float* __restrict__ bgdT,
                       float* __restrict__ n2, size_t sd, size_t sp) {
  int b = blockIdx.z;
  const float* fgb = fg + (size_t)b * CHW;
  const float* bgb = bg + (size_t)b * CHW;
  float* fT = fgdT + (size_t)b * sd;
  float* bT = bgdT + (size_t)b * sd;
  float* n2b = n2 + (size_t)b * sp;
  int p = blockIdx.x * 256 + threadIdx.x;
  if (p >= LQ) return;
  int py = p / ND, px = p % ND;
  const float* fsrc = fgb + (2 * py) * HWD + 2 * px;
  const float* gsrc = bgb + (2 * py) * HWD + 2 * px;
  float s = 0.f;
  for (int c = 0; c < CCH; ++c) {
    float f = fsrc[c * HW2];
    float g = gsrc[c * HW2];
    fT[c * LQ + p] = f;
    bT[c * LQ + p] = g;
    s += g * g;
  }
  n2b[p] = s;
}

// ---------------- K0b: patch norms (rnorm) and mask means (mval)
__global__ void k_aux(const float* __restrict__ n2, const float* __restrict__ mask,
                      float* __restrict__ rnorm, float* __restrict__ mval, size_t sp) {
  int b = blockIdx.z;
  const float* n2b = n2 + (size_t)b * sp;
  const float* mb = mask + (size_t)b * HW2;
  float* rn = rnorm + (size_t)b * sp;
  float* mv = mval + (size_t)b * sp;
  int p = blockIdx.x * 256 + threadIdx.x;
  if (p >= LQ) return;
  int py = p / ND, px = p % ND;
  float ssq = 0.f, ms = 0.f;
  for (int dy = -1; dy <= 1; ++dy)
    for (int dx = -1; dx <= 1; ++dx) {
      int yy = py + dy, xx = px + dx;
      if (yy >= 0 && yy < ND && xx >= 0 && xx < ND) {
        ssq += n2b[yy * ND + xx];
        ms  += mb[(2 * yy) * HWD + 2 * xx];
      }
    }
  rn[p] = 1.0f / sqrtf(ssq + 864.0f * 1e-9f);
  mv[p] = ms * (1.0f / 9.0f);
}

// ---------------- K1: R[q][l] = sum_c fgdT[c][q] * bgdT[c][l]   (fp32, K=96)
__global__ __launch_bounds__(256) void k_rgemm(const float* __restrict__ fgdT,
                                               const float* __restrict__ bgdT,
                                               float* __restrict__ R,
                                               size_t sd, size_t sR) {
  int b = blockIdx.z;
  const float* fT = fgdT + (size_t)b * sd;
  const float* bT = bgdT + (size_t)b * sd;
  float* Rb = R + (size_t)b * sR;
  __shared__ float As[16][64];
  __shared__ float Bs[16][64];
  int l0 = blockIdx.x * 64, q0 = blockIdx.y * 64;
  int tid = threadIdx.x;
  int ty = tid / 16, tx = tid % 16;
  float acc[4][4] = {};
  for (int k0 = 0; k0 < CCH; k0 += 16) {
#pragma unroll
    for (int i = 0; i < 4; ++i) {
      int idx = tid + i * 256;
      int kk = idx >> 6, cc = idx & 63;
      As[kk][cc] = fT[(k0 + kk) * LQ + q0 + cc];
      Bs[kk][cc] = bT[(k0 + kk) * LQ + l0 + cc];
    }
    __syncthreads();
#pragma unroll
    for (int kk = 0; kk < 16; ++kk) {
      float a[4], bb[4];
#pragma unroll
      for (int i = 0; i < 4; ++i) a[i] = As[kk][ty * 4 + i];
#pragma unroll
      for (int j = 0; j < 4; ++j) bb[j] = Bs[kk][tx * 4 + j];
#pragma unroll
      for (int i = 0; i < 4; ++i)
#pragma unroll
        for (int j = 0; j < 4; ++j) acc[i][j] += a[i] * bb[j];
    }
    __syncthreads();
  }
#pragma unroll
  for (int i = 0; i < 4; ++i) {
    float4 v = make_float4(acc[i][0], acc[i][1], acc[i][2], acc[i][3]);
    *(float4*)&Rb[(size_t)(q0 + ty * 4 + i) * LQ + l0 + tx * 4] = v;
  }
}

// ---------------- K2a: T_col (vectorized) — A1 = 3-tap diag, masks on (qx,lx)
__global__ void k_tcolv(const float* __restrict__ R, float* __restrict__ A1, size_t sR) {
  int b = blockIdx.z;
  const float* S = R + (size_t)b * sR;
  float* O = A1 + (size_t)b * sR;
  int t = blockIdx.x * 256 + threadIdx.x;      // LQ*LQ/4 threads
  int id = t * 4;
  int q = id / LQ, l = id % LQ;
  int qx = q % ND, lx0 = l % ND;               // lx0 in {0,4,...,44}; same q for all 4
  float4 c = *(const float4*)(S + id);
  if (qx > 0) {
    float4 m = ld4u(S + id - LQ - 1);
    if (lx0 == 0) m.x = 0.f;
    c.x += m.x; c.y += m.y; c.z += m.z; c.w += m.w;
  }
  if (qx < ND - 1) {
    float4 p = ld4u(S + id + LQ + 1);
    if (lx0 == ND - 4) p.w = 0.f;
    c.x += p.x; c.y += p.y; c.z += p.z; c.w += p.w;
  }
  *(float4*)(O + id) = c;
}

// ---------------- K2b: T_row (+rnorm, vectorized) — masks on (qy,ly), aligned taps
__global__ void k_trowv(const float* __restrict__ A1, const float* __restrict__ rnorm,
                        float* __restrict__ A2, size_t sR, size_t sp) {
  int b = blockIdx.z;
  const float* S = A1 + (size_t)b * sR;
  const float* rn = rnorm + (size_t)b * sp;
  float* O = A2 + (size_t)b * sR;
  int t = blockIdx.x * 256 + threadIdx.x;
  int id = t * 4;
  int q = id / LQ, l = id % LQ;
  int qy = q / ND, ly = l / ND;                // uniform over the 4 elements
  const int OFF = ND * (LQ + 1);               // 110640, %4==0 -> aligned
  float4 c = *(const float4*)(S + id);
  if (qy > 0 && ly > 0) {
    float4 m = *(const float4*)(S + id - OFF);
    c.x += m.x; c.y += m.y; c.z += m.z; c.w += m.w;
  }
  if (qy < ND - 1 && ly < ND - 1) {
    float4 p = *(const float4*)(S + id + OFF);
    c.x += p.x; c.y += p.y; c.z += p.z; c.w += p.w;
  }
  float4 r4 = *(const float4*)(rn + l);
  c.x *= r4.x; c.y *= r4.y; c.z *= r4.z; c.w *= r4.w;
  *(float4*)(O + id) = c;
}

// ---------------- K2c: flat diag fuse (vectorized) — flat bounds on (a,bc)
__global__ void k_fusev(const float* __restrict__ A2, float* __restrict__ F, size_t sR) {
  int b = blockIdx.z;
  const float* S = A2 + (size_t)b * sR;
  float* Fo = F + (size_t)b * sR;
  int t = blockIdx.x * 256 + threadIdx.x;
  int id = t * 4;
  int a = id / LQ, bc0 = id % LQ;
  float4 c = *(const float4*)(S + id);
  if (a > 0) {
    float4 m = ld4u(S + id - LQ - 1);
    if (bc0 == 0) m.x = 0.f;
    c.x += m.x; c.y += m.y; c.z += m.z; c.w += m.w;
  }
  if (a < LQ - 1) {
    float4 p = ld4u(S + id + LQ + 1);
    if (bc0 == LQ - 4) p.w = 0.f;
    c.x += p.x; c.y += p.y; c.z += p.z; c.w += p.w;
  }
  *(float4*)(Fo + id) = c;
}

// ---------------- K3: second fuse (3 taps) + masked softmax over l, write P50 (bf16)
// P50 layout: [guard row 2560][2304 rows x 2560]; col = ly*50+lx; pads zeroed.
__global__ __launch_bounds__(256) void k_softmax(const float* __restrict__ F,
                                                 const float* __restrict__ mval,
                                                 __hip_bfloat16* __restrict__ P50s,
                                                 size_t sR, size_t sp, size_t sP) {
  int b = blockIdx.z;
  const float* Fb = F + (size_t)b * sR;
  const float* mv = mval + (size_t)b * sp;
  __hip_bfloat16* Pb = P50s + (size_t)b * sP + K2P;   // skip guard row
  int q = blockIdx.x;
  int qy = q / ND, qx = q % ND;
  int tid = threadIdx.x;
  __shared__ float red[256];
  int gqv[3]; bool qok[3];
#pragma unroll
  for (int t = 0; t < 3; ++t) {
    int fq = qx * ND + qy + (t - 1);
    qok[t] = (fq >= 0 && fq < LQ);
    gqv[t] = qok[t] ? (fq % ND) * ND + fq / ND : 0;
  }
  float logit[9];
  float vmax = -1e30f;
#pragma unroll
  for (int s = 0; s < 9; ++s) {
    int l = tid + s * 256;
    int ly = l / ND, lx = l % ND;
    float v = 0.f;
#pragma unroll
    for (int t = 0; t < 3; ++t) {
      if (!qok[t]) continue;
      int fl = lx * ND + ly + (t - 1);
      if (fl < 0 || fl >= LQ) continue;
      int gl = (fl % ND) * ND + fl / ND;
      v += Fb[(size_t)gqv[t] * LQ + gl];
    }
    float lg = v * (10.0f * mv[l]);
    logit[s] = lg;
    vmax = fmaxf(vmax, lg);
  }
  red[tid] = vmax;
  __syncthreads();
  for (int w = 128; w > 0; w >>= 1) {
    if (tid < w) red[tid] = fmaxf(red[tid], red[tid + w]);
    __syncthreads();
  }
  float m = red[0];
  __syncthreads();
  float e[9], ssum = 0.f;
#pragma unroll
  for (int s = 0; s < 9; ++s) { e[s] = __expf(logit[s] - m); ssum += e[s]; }
  red[tid] = ssum;
  __syncthreads();
  for (int w = 128; w > 0; w >>= 1) {
    if (tid < w) red[tid] += red[tid + w];
    __syncthreads();
  }
  float inv = 1.0f / red[0];
  __hip_bfloat16 z = __float2bfloat16(0.f);
#pragma unroll
  for (int s = 0; s < 9; ++s) {
    int l = tid + s * 256;
    float p = e[s] * inv * mv[l];
    int col = (l / ND) * 50 + (l % ND);
    Pb[(size_t)q * K2P + col] = __float2bfloat16(p);
  }
  // zero this row's 256 pad columns
  int pc;
  if (tid < 96)        pc = (tid >> 1) * 50 + ND + (tid & 1);   // (m<48, n in {48,49})
  else if (tid < 196)  pc = 2400 + (tid - 96);                  // m in {48,49}
  else                 pc = 2500 + (tid - 196);                 // tail
  Pb[(size_t)q * K2P + pc] = z;
  // block 0 zeroes the guard row (absorbs stencil underflow <= 102 elems)
  if (q == 0)
    for (int i = tid; i < K2P; i += 256) (Pb - K2P)[i] = z;
}

// ---------------- K4a: Q2 = 4-flat-tap stencil of P50 (vectorized, bit-identical order)
__global__ void k_q2v(const __hip_bfloat16* __restrict__ P50s,
                      __hip_bfloat16* __restrict__ Q2, size_t sP, size_t sQ) {
  int bz = blockIdx.z;
  const __hip_bfloat16* P = P50s + (size_t)bz * sP + K2P;
  __hip_bfloat16* Q = Q2 + (size_t)bz * sQ;
  int id = blockIdx.x * 256 + threadIdx.x;     // 2304*320 threads
  int r = id / 320, c8 = (id % 320) * 8;
  int a = r / ND, b = r % ND;
  const __hip_bfloat16* base = P + (size_t)r * K2P + c8;
  float acc[8];
  {  // tap (0,0) — aligned
    unsigned short s[8]; __builtin_memcpy(s, base, 16);
#pragma unroll
    for (int i = 0; i < 8; ++i) {
      unsigned int u = ((unsigned int)s[i]) << 16;
      acc[i] = __builtin_bit_cast(float, u);
    }
  }
  if (b >= 1) {   // tap (du=0,dv=1): offset -(K2P + 2)
    unsigned short s[8]; __builtin_memcpy(s, base - (K2P + 2), 16);
#pragma unroll
    for (int i = 0; i < 8; ++i) {
      unsigned int u = ((unsigned int)s[i]) << 16;
      acc[i] += __builtin_bit_cast(float, u);
    }
  }
  if (a >= 1) {   // tap (du=1,dv=0): offset -(48*K2P + 100)
    unsigned short s[8]; __builtin_memcpy(s, base - (ND * K2P + 100), 16);
#pragma unroll
    for (int i = 0; i < 8; ++i) {
      unsigned int u = ((unsigned int)s[i]) << 16;
      acc[i] += __builtin_bit_cast(float, u);
    }
  }
  if (a >= 1 && b >= 1) {   // tap (du=1,dv=1): offset -(49*K2P + 102)
    unsigned short s[8]; __builtin_memcpy(s, base - ((ND + 1) * K2P + 102), 16);
#pragma unroll
    for (int i = 0; i < 8; ++i) {
      unsigned int u = ((unsigned int)s[i]) << 16;
      acc[i] += __builtin_bit_cast(float, u);
    }
  }
  __hip_bfloat16 o[8];
#pragma unroll
  for (int i = 0; i < 8; ++i) o[i] = __float2bfloat16(acc[i]);
  *(bf16x8*)(Q + (size_t)r * K2P + c8) = *(bf16x8*)o;
}

// ---------------- K4b: B2[(c,s,t),(m,n)] = bgd[c, m+s-1, n+t-1] (zero-padded)
__global__ void k_b2(const float* __restrict__ bgdT, __hip_bfloat16* __restrict__ B2,
                     size_t sd, size_t sB) {
  int b = blockIdx.z;
  const float* gT = bgdT + (size_t)b * sd;
  __hip_bfloat16* Bb = B2 + (size_t)b * sB;
  int id = blockIdx.x * 256 + threadIdx.x;   // over 384*2560
  if (id >= NJ2 * K2P) return;
  int j = id / K2P, col = id % K2P;
  int c = j >> 2, s = (j >> 1) & 1, t = j & 1;
  float v = 0.f;
  if (col < 2500) {
    int m = col / 50, n = col % 50;
    int ry = m + s - 1, rx = n + t - 1;
    if (ry >= 0 && ry < ND && rx >= 0 && rx < ND)
      v = gT[c * LQ + ry * ND + rx];
  }
  Bb[id] = __float2bfloat16(v);
}

// ---------------- K5: bf16 MFMA GEMM: out = (1/16) * Q2 @ B2^T
// 64x64 tiles, 4 waves (2x2, 32x32 each), BK=64, T2 XOR-swizzle via pre-swizzled
// global source (linear gload_lds dest), bijective XCD swizzle (216 = 27*8).
__device__ __forceinline__ void gload16(const void* g, void* l) {
  __builtin_amdgcn_global_load_lds((const __attribute__((address_space(1))) void*)g,
                                   (__attribute__((address_space(3))) void*)l, 16, 0, 0);
}

__global__ __launch_bounds__(256) void k_gemm3(const __hip_bfloat16* __restrict__ A,
                                               const __hip_bfloat16* __restrict__ B,
                                               float* __restrict__ out,
                                               size_t sQ, size_t sB) {
  int bz = blockIdx.z;
  const __hip_bfloat16* Ab = A + (size_t)bz * sQ;
  const __hip_bfloat16* Bb = B + (size_t)bz * sB;
  float* ob = out + (size_t)bz * CHW;
  // XCD swizzle: grid.x = 216 = 8 XCDs * 27 contiguous tiles
  int wg = (blockIdx.x & 7) * 27 + (blockIdx.x >> 3);
  int n0 = (wg % 6) * 64, m0 = (wg / 6) * 64;
  __shared__ __align__(16) __hip_bfloat16 As[2][64 * 64];
  __shared__ __align__(16) __hip_bfloat16 Bs[2][64 * 64];
  int tid = threadIdx.x;
  int w = tid >> 6, lane = tid & 63;
  int wm = w >> 1, wn = w & 1;
  int l3 = lane >> 3, l7 = lane & 7;
  // stage source column pre-swizzle: elem_in_row = (l7*8) ^ (l3*8); l3 == row&7
  int kswz = (l7 * 8) ^ (l3 << 3);
  f32x4 acc[2][2] = {};

  auto STAGE = [&](int buf, int k0) {
#pragma unroll
    for (int i = 0; i < 2; ++i) {
      int chunk = w * 2 + i;                // 8 chunks x 8 rows = 64 rows
      int row = chunk * 8 + l3;
      gload16(Ab + (size_t)(m0 + row) * K2P + k0 + kswz, &As[buf][chunk * 8 * 64]);
      gload16(Bb + (size_t)(n0 + row) * K2P + k0 + kswz, &Bs[buf][chunk * 8 * 64]);
    }
  };

  STAGE(0, 0);
  __syncthreads();
  int cur = 0;
  constexpr int NT = K2P / 64;   // 40
  for (int t = 0; t < NT; ++t) {
    if (t + 1 < NT) STAGE(cur ^ 1, (t + 1) * 64);   // prefetch overlaps compute
#pragma unroll
    for (int kk = 0; kk < 64; kk += 32) {
      bf16x8 af[2], bfr[2];
#pragma unroll
      for (int mi = 0; mi < 2; ++mi) {
        int row = wm * 32 + mi * 16 + (lane & 15);
        int e = (kk + (lane >> 4) * 8) ^ ((row & 7) * 8);   // read-side swizzle
        af[mi] = *(const bf16x8*)(&As[cur][row * 64 + e]);
      }
#pragma unroll
      for (int ni = 0; ni < 2; ++ni) {
        int row = wn * 32 + ni * 16 + (lane & 15);
        int e = (kk + (lane >> 4) * 8) ^ ((row & 7) * 8);
        bfr[ni] = *(const bf16x8*)(&Bs[cur][row * 64 + e]);
      }
#pragma unroll
      for (int mi = 0; mi < 2; ++mi)
#pragma unroll
        for (int ni = 0; ni < 2; ++ni)
          acc[mi][ni] = __builtin_amdgcn_mfma_f32_16x16x32_bf16(af[mi], bfr[ni], acc[mi][ni], 0, 0, 0);
    }
    __syncthreads();
    cur ^= 1;
  }

#pragma unroll
  for (int mi = 0; mi < 2; ++mi)
#pragma unroll
    for (int ni = 0; ni < 2; ++ni)
#pragma unroll
      for (int rr = 0; rr < 4; ++rr) {
        int r_ = m0 + wm * 32 + mi * 16 + (lane >> 4) * 4 + rr;  // M row = a*48+b
        int j  = n0 + wn * 32 + ni * 16 + (lane & 15);           // N col = c*4+s*2+t
        int a = r_ / ND, bcol = r_ % ND;
        int c = j >> 2, s = (j >> 1) & 1, tt = j & 1;
        ob[((size_t)c * HWD + 2 * a + s) * HWD + 2 * bcol + tt] = acc[mi][ni][rr] * 0.0625f;
      }
}

extern "C" void kernel_launch(void* const* d_in, const int* in_sizes, int n_in,
                              void* d_out, int out_size, void* d_ws, size_t ws_size,
                              hipStream_t stream) {
  const float* fg_all = (const float*)d_in[0];
  const float* bg_all = (const float*)d_in[1];
  const float* mask_all = (const float*)d_in[2];
  float* out_all = (float*)d_out;
  float* ws = (float*)d_ws;

  int B = in_sizes[0] / CHW;

  const size_t S_D = (size_t)CCH * LQ;            // 221184 f32
  const size_t S_P = LQ;                          // 2304 f32
  const size_t S_R = (size_t)LQ * LQ;             // 5308416 f32
  const size_t S_P50 = (size_t)(LQ + 1) * K2P;    // 5900800 bf16 (incl guard row)
  const size_t per_floats = S_D * 2 + S_P * 3 + S_R * 2 + S_P50 / 2; // 14016512

  bool batched = ws_size >= (size_t)B * per_floats * 4;
  int na = batched ? B : 1;
  int nb = na;

  float* fgdT  = ws;
  float* bgdT  = fgdT + (size_t)na * S_D;
  float* n2    = bgdT + (size_t)na * S_D;
  float* rnorm = n2 + (size_t)na * S_P;
  float* mval  = rnorm + (size_t)na * S_P;
  float* bufA  = mval + (size_t)na * S_P;              // R, A2, then Q2 (bf16 overlay)
  float* bufB  = bufA + (size_t)na * S_R;              // A1, F, then B2 (bf16 overlay)
  __hip_bfloat16* P50 = (__hip_bfloat16*)(bufB + (size_t)na * S_R);
  __hip_bfloat16* Q2  = (__hip_bfloat16*)bufA;         // 2304*2560 bf16 fits in S_R
  __hip_bfloat16* B2  = (__hip_bfloat16*)bufB;

  size_t sd = batched ? S_D : 0, sp = batched ? S_P : 0, sR = batched ? S_R : 0;
  size_t sP = batched ? S_P50 : 0;
  size_t sQ = batched ? S_R * 2 : 0;
  size_t sB = batched ? S_R * 2 : 0;

  for (int b0 = 0; b0 < B; b0 += nb) {
    const float* fg = fg_all + (size_t)(batched ? 0 : b0) * CHW;
    const float* bg = bg_all + (size_t)(batched ? 0 : b0) * CHW;
    const float* mask = mask_all + (size_t)(batched ? 0 : b0) * HW2;
    float* out = out_all + (size_t)(batched ? 0 : b0) * CHW;

    hipLaunchKernelGGL(k_down, dim3(9, 1, nb), dim3(256), 0, stream,
                       fg, bg, fgdT, bgdT, n2, sd, sp);
    hipLaunchKernelGGL(k_aux, dim3(9, 1, nb), dim3(256), 0, stream,
                       n2, mask, rnorm, mval, sp);
    hipLaunchKernelGGL(k_rgemm, dim3(36, 36, nb), dim3(256), 0, stream,
                       fgdT, bgdT, bufA, sd, sR);
    hipLaunchKernelGGL(k_tcolv, dim3(5184, 1, nb), dim3(256), 0, stream,
                       bufA, bufB, sR);
    hipLaunchKernelGGL(k_trowv, dim3(5184, 1, nb), dim3(256), 0, stream,
                       bufB, rnorm, bufA, sR, sp);
    hipLaunchKernelGGL(k_fusev, dim3(5184, 1, nb), dim3(256), 0, stream,
                       bufA, bufB, sR);
    hipLaunchKernelGGL(k_softmax, dim3(2304, 1, nb), dim3(256), 0, stream,
                       bufB, mval, P50, sR, sp, sP);
    hipLaunchKernelGGL(k_q2v, dim3(2880, 1, nb), dim3(256), 0, stream,
                       P50, Q2, sP, sQ);
    hipLaunchKernelGGL(k_b2, dim3(3840, 1, nb), dim3(256), 0, stream,
                       bgdT, B2, sd, sB);
    hipLaunchKernelGGL(k_gemm3, dim3(216, 1, nb), dim3(256), 0, stream,
                       Q2, B2, out, sQ, sB);
  }
}

// Round 7
// 341.045 us; speedup vs baseline: 2.2299x; 1.0442x over previous
//
#include <hip/hip_runtime.h>
#include <hip/hip_bf16.h>
#include <cstdint>

#define ND 48
#define LQ 2304      // 48*48
#define CCH 96
#define HWD 96
#define CHW (CCH*HWD*HWD)   // 884736
#define HW2 (HWD*HWD)       // 9216
#define K2P 2560     // padded K (50-grid: 2500 live, cols>=2500 zero)
#define NJ2 384      // 96 ch * 4 (s,t)
#define KSP 384      // split-GEMM K (288 live = 3 parts x 96, padded to 3x128)

typedef __attribute__((ext_vector_type(8))) short bf16x8;
typedef __attribute__((ext_vector_type(4))) float f32x4;

__device__ __forceinline__ float4 ld4u(const float* p) {  // 4B-aligned float4 load
  float4 v; __builtin_memcpy(&v, p, 16); return v;
}

// ---------------- K0: downsample fg/bg to (c,p) layout + per-pos squared norm of bgd
__global__ void k_down(const float* __restrict__ fg, const float* __restrict__ bg,
                       float* __restrict__ fgdT, float* __restrict__ bgdT,
                       float* __restrict__ n2, size_t sd, size_t sp) {
  int b = blockIdx.z;
  const float* fgb = fg + (size_t)b * CHW;
  const float* bgb = bg + (size_t)b * CHW;
  float* fT = fgdT + (size_t)b * sd;
  float* bT = bgdT + (size_t)b * sd;
  float* n2b = n2 + (size_t)b * sp;
  int p = blockIdx.x * 256 + threadIdx.x;
  if (p >= LQ) return;
  int py = p / ND, px = p % ND;
  const float* fsrc = fgb + (2 * py) * HWD + 2 * px;
  const float* gsrc = bgb + (2 * py) * HWD + 2 * px;
  float s = 0.f;
  for (int c = 0; c < CCH; ++c) {
    float f = fsrc[c * HW2];
    float g = gsrc[c * HW2];
    fT[c * LQ + p] = f;
    bT[c * LQ + p] = g;
    s += g * g;
  }
  n2b[p] = s;
}

// ---------------- K0b: patch norms (rnorm) and mask means (mval)
__global__ void k_aux(const float* __restrict__ n2, const float* __restrict__ mask,
                      float* __restrict__ rnorm, float* __restrict__ mval, size_t sp) {
  int b = blockIdx.z;
  const float* n2b = n2 + (size_t)b * sp;
  const float* mb = mask + (size_t)b * HW2;
  float* rn = rnorm + (size_t)b * sp;
  float* mv = mval + (size_t)b * sp;
  int p = blockIdx.x * 256 + threadIdx.x;
  if (p >= LQ) return;
  int py = p / ND, px = p % ND;
  float ssq = 0.f, ms = 0.f;
  for (int dy = -1; dy <= 1; ++dy)
    for (int dx = -1; dx <= 1; ++dx) {
      int yy = py + dy, xx = px + dx;
      if (yy >= 0 && yy < ND && xx >= 0 && xx < ND) {
        ssq += n2b[yy * ND + xx];
        ms  += mb[(2 * yy) * HWD + 2 * xx];
      }
    }
  rn[p] = 1.0f / sqrtf(ssq + 864.0f * 1e-9f);
  mv[p] = ms * (1.0f / 9.0f);
}

// ---------------- K1a: build split operands for MFMA rgemm
// A[q][k]: k=c+96*part, parts {f_hi, f_hi, f_lo}; B[l][k]: parts {g_hi, g_lo, g_hi};
// k in [288,384) zeroed. Both [2304][384] bf16, written into the (dead) P50 region.
__global__ __launch_bounds__(256) void k_split(const float* __restrict__ fgdT,
                                               const float* __restrict__ bgdT,
                                               __hip_bfloat16* __restrict__ AB,
                                               size_t sd, size_t sAB) {
  int b = blockIdx.z;
  const float* fT = fgdT + (size_t)b * sd;
  const float* gT = bgdT + (size_t)b * sd;
  __hip_bfloat16* Ao = AB + (size_t)b * sAB;
  __hip_bfloat16* Bo = Ao + (size_t)LQ * KSP;
  __shared__ float fs[96 * 65], gs[96 * 65];
  int q0 = blockIdx.x * 64;
  int tid = threadIdx.x;
#pragma unroll
  for (int i = 0; i < 24; ++i) {
    int e = i * 256 + tid;
    int c = e >> 6, qq = e & 63;
    fs[c * 65 + qq] = fT[c * LQ + q0 + qq];
    gs[c * 65 + qq] = gT[c * LQ + q0 + qq];
  }
  __syncthreads();
  // 64 rows x 96 short4 (=384 shorts) per matrix
  for (int i = 0; i < 24; ++i) {
    int e = i * 256 + tid;               // 6144
    int qq = e / 96, k4 = (e % 96) * 4;
    unsigned short a4[4], b4[4];
    if (k4 < 288) {
      int part = k4 / 96, c = k4 % 96;
#pragma unroll
      for (int j = 0; j < 4; ++j) {
        float f = fs[(c + j) * 65 + qq];
        float g = gs[(c + j) * 65 + qq];
        __hip_bfloat16 fh = __float2bfloat16(f);
        __hip_bfloat16 gh = __float2bfloat16(g);
        __hip_bfloat16 fl = __float2bfloat16(f - __bfloat162float(fh));
        __hip_bfloat16 gl = __float2bfloat16(g - __bfloat162float(gh));
        __hip_bfloat16 av = (part == 2) ? fl : fh;              // {hi, hi, lo}
        __hip_bfloat16 bv = (part == 1) ? gl : gh;              // {hi, lo, hi}
        a4[j] = *(unsigned short*)&av;
        b4[j] = *(unsigned short*)&bv;
      }
    } else {
      a4[0] = a4[1] = a4[2] = a4[3] = 0;
      b4[0] = b4[1] = b4[2] = b4[3] = 0;
    }
    __builtin_memcpy(&Ao[(size_t)(q0 + qq) * KSP + k4], a4, 8);
    __builtin_memcpy(&Bo[(size_t)(q0 + qq) * KSP + k4], b4, 8);
  }
}

// ---------------- K1b: R[q][l] = sum_k A[q,k]*B[l,k]  (MFMA bf16 split, K=384)
__device__ __forceinline__ void gload16(const void* g, void* l) {
  __builtin_amdgcn_global_load_lds((const __attribute__((address_space(1))) void*)g,
                                   (__attribute__((address_space(3))) void*)l, 16, 0, 0);
}

__global__ __launch_bounds__(256) void k_rgemm_mfma(const __hip_bfloat16* __restrict__ AB,
                                                    float* __restrict__ R,
                                                    size_t sAB, size_t sR) {
  int bz = blockIdx.z;
  const __hip_bfloat16* Aq = AB + (size_t)bz * sAB;
  const __hip_bfloat16* Bq = Aq + (size_t)LQ * KSP;
  float* Rb = R + (size_t)bz * sR;
  __shared__ __align__(16) __hip_bfloat16 As[2][64 * 128];
  __shared__ __align__(16) __hip_bfloat16 Bs[2][64 * 128];
  int m0 = blockIdx.y * 64, n0 = blockIdx.x * 64;
  int tid = threadIdx.x;
  int w = tid >> 6, lane = tid & 63;
  int wm = w >> 1, wn = w & 1;
  f32x4 acc[2][2] = {};

  auto STAGE = [&](int buf, int k0) {
#pragma unroll
    for (int i = 0; i < 4; ++i) {
      int g = i * 256 + tid;
      int row = g >> 4, slot = g & 15;
      int ks = 8 * (slot ^ (row & 7));          // pre-swizzled source column
      gload16(Aq + (size_t)(m0 + row) * KSP + k0 + ks, &As[buf][g * 8]);
      gload16(Bq + (size_t)(n0 + row) * KSP + k0 + ks, &Bs[buf][g * 8]);
    }
  };

  STAGE(0, 0);
  __syncthreads();
  int cur = 0;
  for (int t = 0; t < 3; ++t) {
    if (t + 1 < 3) STAGE(cur ^ 1, (t + 1) * 128);
#pragma unroll
    for (int kk = 0; kk < 128; kk += 32) {
      bf16x8 af[2], bfr[2];
#pragma unroll
      for (int mi = 0; mi < 2; ++mi) {
        int row = wm * 32 + mi * 16 + (lane & 15);
        int e = (kk + (lane >> 4) * 8) ^ ((row & 7) * 8);   // read-side swizzle
        af[mi] = *(const bf16x8*)(&As[cur][row * 128 + e]);
      }
#pragma unroll
      for (int ni = 0; ni < 2; ++ni) {
        int row = wn * 32 + ni * 16 + (lane & 15);
        int e = (kk + (lane >> 4) * 8) ^ ((row & 7) * 8);
        bfr[ni] = *(const bf16x8*)(&Bs[cur][row * 128 + e]);
      }
#pragma unroll
      for (int mi = 0; mi < 2; ++mi)
#pragma unroll
        for (int ni = 0; ni < 2; ++ni)
          acc[mi][ni] = __builtin_amdgcn_mfma_f32_16x16x32_bf16(af[mi], bfr[ni], acc[mi][ni], 0, 0, 0);
    }
    __syncthreads();
    cur ^= 1;
  }

#pragma unroll
  for (int mi = 0; mi < 2; ++mi)
#pragma unroll
    for (int ni = 0; ni < 2; ++ni)
#pragma unroll
      for (int rr = 0; rr < 4; ++rr) {
        int row = m0 + wm * 32 + mi * 16 + (lane >> 4) * 4 + rr;
        int col = n0 + wn * 32 + ni * 16 + (lane & 15);
        Rb[(size_t)row * LQ + col] = acc[mi][ni][rr];
      }
}

// ---------------- K2a: T_col (vectorized) — A1 = 3-tap diag, masks on (qx,lx)
__global__ void k_tcolv(const float* __restrict__ R, float* __restrict__ A1, size_t sR) {
  int b = blockIdx.z;
  const float* S = R + (size_t)b * sR;
  float* O = A1 + (size_t)b * sR;
  int t = blockIdx.x * 256 + threadIdx.x;      // LQ*LQ/4 threads
  int id = t * 4;
  int q = id / LQ, l = id % LQ;
  int qx = q % ND, lx0 = l % ND;               // lx0 in {0,4,...,44}; same q for all 4
  float4 c = *(const float4*)(S + id);
  if (qx > 0) {
    float4 m = ld4u(S + id - LQ - 1);
    if (lx0 == 0) m.x = 0.f;
    c.x += m.x; c.y += m.y; c.z += m.z; c.w += m.w;
  }
  if (qx < ND - 1) {
    float4 p = ld4u(S + id + LQ + 1);
    if (lx0 == ND - 4) p.w = 0.f;
    c.x += p.x; c.y += p.y; c.z += p.z; c.w += p.w;
  }
  *(float4*)(O + id) = c;
}

// ---------------- K2b: T_row (+rnorm, vectorized) — masks on (qy,ly), aligned taps
__global__ void k_trowv(const float* __restrict__ A1, const float* __restrict__ rnorm,
                        float* __restrict__ A2, size_t sR, size_t sp) {
  int b = blockIdx.z;
  const float* S = A1 + (size_t)b * sR;
  const float* rn = rnorm + (size_t)b * sp;
  float* O = A2 + (size_t)b * sR;
  int t = blockIdx.x * 256 + threadIdx.x;
  int id = t * 4;
  int q = id / LQ, l = id % LQ;
  int qy = q / ND, ly = l / ND;                // uniform over the 4 elements
  const int OFF = ND * (LQ + 1);               // 110640, %4==0 -> aligned
  float4 c = *(const float4*)(S + id);
  if (qy > 0 && ly > 0) {
    float4 m = *(const float4*)(S + id - OFF);
    c.x += m.x; c.y += m.y; c.z += m.z; c.w += m.w;
  }
  if (qy < ND - 1 && ly < ND - 1) {
    float4 p = *(const float4*)(S + id + OFF);
    c.x += p.x; c.y += p.y; c.z += p.z; c.w += p.w;
  }
  float4 r4 = *(const float4*)(rn + l);
  c.x *= r4.x; c.y *= r4.y; c.z *= r4.z; c.w *= r4.w;
  *(float4*)(O + id) = c;
}

// ---------------- K2c: flat diag fuse (vectorized) — flat bounds on (a,bc)
__global__ void k_fusev(const float* __restrict__ A2, float* __restrict__ F, size_t sR) {
  int b = blockIdx.z;
  const float* S = A2 + (size_t)b * sR;
  float* Fo = F + (size_t)b * sR;
  int t = blockIdx.x * 256 + threadIdx.x;
  int id = t * 4;
  int a = id / LQ, bc0 = id % LQ;
  float4 c = *(const float4*)(S + id);
  if (a > 0) {
    float4 m = ld4u(S + id - LQ - 1);
    if (bc0 == 0) m.x = 0.f;
    c.x += m.x; c.y += m.y; c.z += m.z; c.w += m.w;
  }
  if (a < LQ - 1) {
    float4 p = ld4u(S + id + LQ + 1);
    if (bc0 == LQ - 4) p.w = 0.f;
    c.x += p.x; c.y += p.y; c.z += p.z; c.w += p.w;
  }
  *(float4*)(Fo + id) = c;
}

// ---------------- K3: second fuse (3 taps) + masked softmax over l, write P50 (bf16)
// P50 layout: [guard row 2560][2304 rows x 2560]; col = ly*50+lx; pads zeroed.
__global__ __launch_bounds__(256) void k_softmax(const float* __restrict__ F,
                                                 const float* __restrict__ mval,
                                                 __hip_bfloat16* __restrict__ P50s,
                                                 size_t sR, size_t sp, size_t sP) {
  int b = blockIdx.z;
  const float* Fb = F + (size_t)b * sR;
  const float* mv = mval + (size_t)b * sp;
  __hip_bfloat16* Pb = P50s + (size_t)b * sP + K2P;   // skip guard row
  int q = blockIdx.x;
  int qy = q / ND, qx = q % ND;
  int tid = threadIdx.x;
  __shared__ float red[256];
  int gqv[3]; bool qok[3];
#pragma unroll
  for (int t = 0; t < 3; ++t) {
    int fq = qx * ND + qy + (t - 1);
    qok[t] = (fq >= 0 && fq < LQ);
    gqv[t] = qok[t] ? (fq % ND) * ND + fq / ND : 0;
  }
  float logit[9];
  float vmax = -1e30f;
#pragma unroll
  for (int s = 0; s < 9; ++s) {
    int l = tid + s * 256;
    int ly = l / ND, lx = l % ND;
    float v = 0.f;
#pragma unroll
    for (int t = 0; t < 3; ++t) {
      if (!qok[t]) continue;
      int fl = lx * ND + ly + (t - 1);
      if (fl < 0 || fl >= LQ) continue;
      int gl = (fl % ND) * ND + fl / ND;
      v += Fb[(size_t)gqv[t] * LQ + gl];
    }
    float lg = v * (10.0f * mv[l]);
    logit[s] = lg;
    vmax = fmaxf(vmax, lg);
  }
  red[tid] = vmax;
  __syncthreads();
  for (int w = 128; w > 0; w >>= 1) {
    if (tid < w) red[tid] = fmaxf(red[tid], red[tid + w]);
    __syncthreads();
  }
  float m = red[0];
  __syncthreads();
  float e[9], ssum = 0.f;
#pragma unroll
  for (int s = 0; s < 9; ++s) { e[s] = __expf(logit[s] - m); ssum += e[s]; }
  red[tid] = ssum;
  __syncthreads();
  for (int w = 128; w > 0; w >>= 1) {
    if (tid < w) red[tid] += red[tid + w];
    __syncthreads();
  }
  float inv = 1.0f / red[0];
  __hip_bfloat16 z = __float2bfloat16(0.f);
#pragma unroll
  for (int s = 0; s < 9; ++s) {
    int l = tid + s * 256;
    float p = e[s] * inv * mv[l];
    int col = (l / ND) * 50 + (l % ND);
    Pb[(size_t)q * K2P + col] = __float2bfloat16(p);
  }
  // zero this row's 256 pad columns
  int pc;
  if (tid < 96)        pc = (tid >> 1) * 50 + ND + (tid & 1);   // (m<48, n in {48,49})
  else if (tid < 196)  pc = 2400 + (tid - 96);                  // m in {48,49}
  else                 pc = 2500 + (tid - 196);                 // tail
  Pb[(size_t)q * K2P + pc] = z;
  // block 0 zeroes the guard row (absorbs stencil underflow <= 102 elems)
  if (q == 0)
    for (int i = tid; i < K2P; i += 256) (Pb - K2P)[i] = z;
}

// ---------------- K4a: Q2 = 4-flat-tap stencil of P50 (vectorized, bit-identical order)
__global__ void k_q2v(const __hip_bfloat16* __restrict__ P50s,
                      __hip_bfloat16* __restrict__ Q2, size_t sP, size_t sQ) {
  int bz = blockIdx.z;
  const __hip_bfloat16* P = P50s + (size_t)bz * sP + K2P;
  __hip_bfloat16* Q = Q2 + (size_t)bz * sQ;
  int id = blockIdx.x * 256 + threadIdx.x;     // 2304*320 threads
  int r = id / 320, c8 = (id % 320) * 8;
  int a = r / ND, b = r % ND;
  const __hip_bfloat16* base = P + (size_t)r * K2P + c8;
  float acc[8];
  {  // tap (0,0) — aligned
    unsigned short s[8]; __builtin_memcpy(s, base, 16);
#pragma unroll
    for (int i = 0; i < 8; ++i) {
      unsigned int u = ((unsigned int)s[i]) << 16;
      acc[i] = __builtin_bit_cast(float, u);
    }
  }
  if (b >= 1) {   // tap (du=0,dv=1): offset -(K2P + 2)
    unsigned short s[8]; __builtin_memcpy(s, base - (K2P + 2), 16);
#pragma unroll
    for (int i = 0; i < 8; ++i) {
      unsigned int u = ((unsigned int)s[i]) << 16;
      acc[i] += __builtin_bit_cast(float, u);
    }
  }
  if (a >= 1) {   // tap (du=1,dv=0): offset -(48*K2P + 100)
    unsigned short s[8]; __builtin_memcpy(s, base - (ND * K2P + 100), 16);
#pragma unroll
    for (int i = 0; i < 8; ++i) {
      unsigned int u = ((unsigned int)s[i]) << 16;
      acc[i] += __builtin_bit_cast(float, u);
    }
  }
  if (a >= 1 && b >= 1) {   // tap (du=1,dv=1): offset -(49*K2P + 102)
    unsigned short s[8]; __builtin_memcpy(s, base - ((ND + 1) * K2P + 102), 16);
#pragma unroll
    for (int i = 0; i < 8; ++i) {
      unsigned int u = ((unsigned int)s[i]) << 16;
      acc[i] += __builtin_bit_cast(float, u);
    }
  }
  __hip_bfloat16 o[8];
#pragma unroll
  for (int i = 0; i < 8; ++i) o[i] = __float2bfloat16(acc[i]);
  *(bf16x8*)(Q + (size_t)r * K2P + c8) = *(bf16x8*)o;
}

// ---------------- K4b: B2[(c,s,t),(m,n)] = bgd[c, m+s-1, n+t-1] (zero-padded)
__global__ void k_b2(const float* __restrict__ bgdT, __hip_bfloat16* __restrict__ B2,
                     size_t sd, size_t sB) {
  int b = blockIdx.z;
  const float* gT = bgdT + (size_t)b * sd;
  __hip_bfloat16* Bb = B2 + (size_t)b * sB;
  int id = blockIdx.x * 256 + threadIdx.x;   // over 384*2560
  if (id >= NJ2 * K2P) return;
  int j = id / K2P, col = id % K2P;
  int c = j >> 2, s = (j >> 1) & 1, t = j & 1;
  float v = 0.f;
  if (col < 2500) {
    int m = col / 50, n = col % 50;
    int ry = m + s - 1, rx = n + t - 1;
    if (ry >= 0 && ry < ND && rx >= 0 && rx < ND)
      v = gT[c * LQ + ry * ND + rx];
  }
  Bb[id] = __float2bfloat16(v);
}

// ---------------- K5: bf16 MFMA GEMM: out = (1/16) * Q2 @ B2^T
// 64x64 tiles, 4 waves (2x2, 32x32 each), BK=64, T2 XOR-swizzle via pre-swizzled
// global source (linear gload_lds dest), bijective XCD swizzle (216 = 27*8).
__global__ __launch_bounds__(256) void k_gemm3(const __hip_bfloat16* __restrict__ A,
                                               const __hip_bfloat16* __restrict__ B,
                                               float* __restrict__ out,
                                               size_t sQ, size_t sB) {
  int bz = blockIdx.z;
  const __hip_bfloat16* Ab = A + (size_t)bz * sQ;
  const __hip_bfloat16* Bb = B + (size_t)bz * sB;
  float* ob = out + (size_t)bz * CHW;
  // XCD swizzle: grid.x = 216 = 8 XCDs * 27 contiguous tiles
  int wg = (blockIdx.x & 7) * 27 + (blockIdx.x >> 3);
  int n0 = (wg % 6) * 64, m0 = (wg / 6) * 64;
  __shared__ __align__(16) __hip_bfloat16 As[2][64 * 64];
  __shared__ __align__(16) __hip_bfloat16 Bs[2][64 * 64];
  int tid = threadIdx.x;
  int w = tid >> 6, lane = tid & 63;
  int wm = w >> 1, wn = w & 1;
  int l3 = lane >> 3, l7 = lane & 7;
  // stage source column pre-swizzle: elem_in_row = (l7*8) ^ (l3*8); l3 == row&7
  int kswz = (l7 * 8) ^ (l3 << 3);
  f32x4 acc[2][2] = {};

  auto STAGE = [&](int buf, int k0) {
#pragma unroll
    for (int i = 0; i < 2; ++i) {
      int chunk = w * 2 + i;                // 8 chunks x 8 rows = 64 rows
      int row = chunk * 8 + l3;
      gload16(Ab + (size_t)(m0 + row) * K2P + k0 + kswz, &As[buf][chunk * 8 * 64]);
      gload16(Bb + (size_t)(n0 + row) * K2P + k0 + kswz, &Bs[buf][chunk * 8 * 64]);
    }
  };

  STAGE(0, 0);
  __syncthreads();
  int cur = 0;
  constexpr int NT = K2P / 64;   // 40
  for (int t = 0; t < NT; ++t) {
    if (t + 1 < NT) STAGE(cur ^ 1, (t + 1) * 64);   // prefetch overlaps compute
#pragma unroll
    for (int kk = 0; kk < 64; kk += 32) {
      bf16x8 af[2], bfr[2];
#pragma unroll
      for (int mi = 0; mi < 2; ++mi) {
        int row = wm * 32 + mi * 16 + (lane & 15);
        int e = (kk + (lane >> 4) * 8) ^ ((row & 7) * 8);   // read-side swizzle
        af[mi] = *(const bf16x8*)(&As[cur][row * 64 + e]);
      }
#pragma unroll
      for (int ni = 0; ni < 2; ++ni) {
        int row = wn * 32 + ni * 16 + (lane & 15);
        int e = (kk + (lane >> 4) * 8) ^ ((row & 7) * 8);
        bfr[ni] = *(const bf16x8*)(&Bs[cur][row * 64 + e]);
      }
#pragma unroll
      for (int mi = 0; mi < 2; ++mi)
#pragma unroll
        for (int ni = 0; ni < 2; ++ni)
          acc[mi][ni] = __builtin_amdgcn_mfma_f32_16x16x32_bf16(af[mi], bfr[ni], acc[mi][ni], 0, 0, 0);
    }
    __syncthreads();
    cur ^= 1;
  }

#pragma unroll
  for (int mi = 0; mi < 2; ++mi)
#pragma unroll
    for (int ni = 0; ni < 2; ++ni)
#pragma unroll
      for (int rr = 0; rr < 4; ++rr) {
        int r_ = m0 + wm * 32 + mi * 16 + (lane >> 4) * 4 + rr;  // M row = a*48+b
        int j  = n0 + wn * 32 + ni * 16 + (lane & 15);           // N col = c*4+s*2+t
        int a = r_ / ND, bcol = r_ % ND;
        int c = j >> 2, s = (j >> 1) & 1, tt = j & 1;
        ob[((size_t)c * HWD + 2 * a + s) * HWD + 2 * bcol + tt] = acc[mi][ni][rr] * 0.0625f;
      }
}

extern "C" void kernel_launch(void* const* d_in, const int* in_sizes, int n_in,
                              void* d_out, int out_size, void* d_ws, size_t ws_size,
                              hipStream_t stream) {
  const float* fg_all = (const float*)d_in[0];
  const float* bg_all = (const float*)d_in[1];
  const float* mask_all = (const float*)d_in[2];
  float* out_all = (float*)d_out;
  float* ws = (float*)d_ws;

  int B = in_sizes[0] / CHW;

  const size_t S_D = (size_t)CCH * LQ;            // 221184 f32
  const size_t S_P = LQ;                          // 2304 f32
  const size_t S_R = (size_t)LQ * LQ;             // 5308416 f32
  const size_t S_P50 = (size_t)(LQ + 1) * K2P;    // 5900800 bf16 (incl guard row)
  const size_t per_floats = S_D * 2 + S_P * 3 + S_R * 2 + S_P50 / 2; // 14016512

  bool batched = ws_size >= (size_t)B * per_floats * 4;
  int na = batched ? B : 1;
  int nb = na;

  float* fgdT  = ws;
  float* bgdT  = fgdT + (size_t)na * S_D;
  float* n2    = bgdT + (size_t)na * S_D;
  float* rnorm = n2 + (size_t)na * S_P;
  float* mval  = rnorm + (size_t)na * S_P;
  float* bufA  = mval + (size_t)na * S_P;              // R, A2, then Q2 (bf16 overlay)
  float* bufB  = bufA + (size_t)na * S_R;              // A1, F, then B2 (bf16 overlay)
  __hip_bfloat16* P50 = (__hip_bfloat16*)(bufB + (size_t)na * S_R);
  __hip_bfloat16* Q2  = (__hip_bfloat16*)bufA;         // 2304*2560 bf16 fits in S_R
  __hip_bfloat16* B2  = (__hip_bfloat16*)bufB;
  // split operands (2 x 2304x384 bf16 = 1.77M shorts) overlay the then-dead P50 region
  __hip_bfloat16* ABs = P50;

  size_t sd = batched ? S_D : 0, sp = batched ? S_P : 0, sR = batched ? S_R : 0;
  size_t sP = batched ? S_P50 : 0;
  size_t sQ = batched ? S_R * 2 : 0;
  size_t sB = batched ? S_R * 2 : 0;

  for (int b0 = 0; b0 < B; b0 += nb) {
    const float* fg = fg_all + (size_t)(batched ? 0 : b0) * CHW;
    const float* bg = bg_all + (size_t)(batched ? 0 : b0) * CHW;
    const float* mask = mask_all + (size_t)(batched ? 0 : b0) * HW2;
    float* out = out_all + (size_t)(batched ? 0 : b0) * CHW;

    hipLaunchKernelGGL(k_down, dim3(9, 1, nb), dim3(256), 0, stream,
                       fg, bg, fgdT, bgdT, n2, sd, sp);
    hipLaunchKernelGGL(k_aux, dim3(9, 1, nb), dim3(256), 0, stream,
                       n2, mask, rnorm, mval, sp);
    hipLaunchKernelGGL(k_split, dim3(36, 1, nb), dim3(256), 0, stream,
                       fgdT, bgdT, ABs, sd, sP);
    hipLaunchKernelGGL(k_rgemm_mfma, dim3(36, 36, nb), dim3(256), 0, stream,
                       ABs, bufA, sP, sR);
    hipLaunchKernelGGL(k_tcolv, dim3(5184, 1, nb), dim3(256), 0, stream,
                       bufA, bufB, sR);
    hipLaunchKernelGGL(k_trowv, dim3(5184, 1, nb), dim3(256), 0, stream,
                       bufB, rnorm, bufA, sR, sp);
    hipLaunchKernelGGL(k_fusev, dim3(5184, 1, nb), dim3(256), 0, stream,
                       bufA, bufB, sR);
    hipLaunchKernelGGL(k_softmax, dim3(2304, 1, nb), dim3(256), 0, stream,
                       bufB, mval, P50, sR, sp, sP);
    hipLaunchKernelGGL(k_q2v, dim3(2880, 1, nb), dim3(256), 0, stream,
                       P50, Q2, sP, sQ);
    hipLaunchKernelGGL(k_b2, dim3(3840, 1, nb), dim3(256), 0, stream,
                       bgdT, B2, sd, sB);
    hipLaunchKernelGGL(k_gemm3, dim3(216, 1, nb), dim3(256), 0, stream,
                       Q2, B2, out, sQ, sB);
  }
}